// Round 10
// baseline (612.563 us; speedup 1.0000x reference)
//
#include <hip/hip_runtime.h>
#include <hip/hip_bf16.h>
#include <math.h>

#define B_   4
#define T_   512
#define D_   384
#define S_   32
#define E_   6
#define H_   512
#define R_   5
#define L_   2
#define DI_  768
#define DTR_ 24
#define BT_  2048
#define XPN_ 88   // DTR + 2*S
#define SCH  64   // scan time-chunk
#define PIT  40   // GEMM LDS row pitch in ushorts (80 B)
#define SPD  10   // scan sdx pitch (floats): [t][{dt,x}x4ch], broadcast b64 reads
#define SPB  66   // scan sbc pitch (floats): [t][{B,C}x32s], b64 reads 2-way free

typedef short s8v __attribute__((ext_vector_type(8)));
typedef float f32x4 __attribute__((ext_vector_type(4)));
typedef ushort u16x8 __attribute__((ext_vector_type(8)));

__device__ __forceinline__ float siluf(float x) { return x / (1.f + __expf(-x)); }
__device__ __forceinline__ ushort f2b(float f) {
    unsigned u = __float_as_uint(f);
    return (ushort)((u + 0x7FFFu + ((u >> 16) & 1u)) >> 16);
}
__device__ __forceinline__ float b2f(ushort h) { return __uint_as_float(((unsigned)h) << 16); }

// ---------------- weight pre-conversion ----------------
#define CN0 1179648L  // in_w
#define CN1 135168L   // xp_w
#define CN2 36864L    // dt_w
#define CN3 589824L   // out_w
#define CN4 2359296L  // e_w1
#define CN5 2359296L  // e_w2
#define CN6 294912L   // r_w1[:384,:] hi/lo (2 layers)
__global__ void conv_k(const float* __restrict__ in_w, const float* __restrict__ xp_w,
                       const float* __restrict__ dt_w, const float* __restrict__ out_w,
                       const float* __restrict__ e_w1, const float* __restrict__ e_w2,
                       const float* __restrict__ r_w1,
                       ushort* __restrict__ in_wb, ushort* __restrict__ xp_wb,
                       ushort* __restrict__ dt_wb, ushort* __restrict__ out_wb,
                       ushort* __restrict__ e1b, ushort* __restrict__ e2b,
                       ushort* __restrict__ r1h, ushort* __restrict__ r1l)
{
    const long total = CN0 + CN1 + CN2 + CN3 + CN4 + CN5 + CN6;
    long stride = (long)gridDim.x * 256;
    for (long i = (long)blockIdx.x * 256 + threadIdx.x; i < total; i += stride) {
        long j = i;
        if (j < CN0) { in_wb[j] = f2b(in_w[j]); continue; }
        j -= CN0;
        if (j < CN1) { xp_wb[j] = f2b(xp_w[j]); continue; }
        j -= CN1;
        if (j < CN2) { dt_wb[j] = f2b(dt_w[j]); continue; }
        j -= CN2;
        if (j < CN3) { out_wb[j] = f2b(out_w[j]); continue; }
        j -= CN3;
        if (j < CN4) { e1b[j] = f2b(e_w1[j]); continue; }
        j -= CN4;
        if (j < CN5) { e2b[j] = f2b(e_w2[j]); continue; }
        j -= CN5;
        {
            long l = j / 147456, rem = j - l * 147456;
            float v = r_w1[l * (long)((D_ + R_) * D_) + rem];
            ushort hv = f2b(v);
            r1h[j] = hv;
            r1l[j] = f2b(v - b2f(hv));
        }
    }
}

// ---------------- FiLM ----------------
__global__ void film_k(const float* __restrict__ regime, const float* __restrict__ w1,
                       const float* __restrict__ b1, const float* __restrict__ w2,
                       const float* __restrict__ b2, float* __restrict__ gb,
                       float* __restrict__ stats)
{
    int b = blockIdx.x;
    int tid = threadIdx.x;
    if (b == 0 && tid < 40) stats[tid] = 0.f;
    __shared__ float t1[D_];
    if (tid < D_) {
        float a = b1[tid];
        for (int r = 0; r < R_; r++) a += regime[b * R_ + r] * w1[r * D_ + tid];
        t1[tid] = siluf(a);
    }
    __syncthreads();
    float a = b2[tid];
    for (int d = 0; d < D_; d++) a += t1[d] * w2[d * (2 * D_) + tid];
    gb[b * (2 * D_) + tid] = a;
}

__global__ void film_apply_k(const float* __restrict__ x, const float* __restrict__ gb,
                             float* __restrict__ h)
{
    int i = blockIdx.x * 256 + threadIdx.x;
    if (i >= B_ * T_ * D_) return;
    int b = i / (T_ * D_);
    int d = i % D_;
    h[i] = x[i] * (1.f + gb[b * (2 * D_) + d]) + gb[b * (2 * D_) + D_ + d];
}

// ---------------- LayerNorm: MODE 0 = f32 out, 1 = bf16 out, 2 = bf16 hi+lo ----------------
template<int MODE>
__global__ __launch_bounds__(256) void ln_k(const float* __restrict__ in,
                                            const float* __restrict__ g, const float* __restrict__ b,
                                            float* __restrict__ outF,
                                            ushort* __restrict__ outH, ushort* __restrict__ outL)
{
    int row = blockIdx.x;
    int tid = threadIdx.x;
    const float* x = in + (size_t)row * D_;
    float v0 = x[tid];
    float v1 = (tid < D_ - 256) ? x[256 + tid] : 0.f;
    float s = v0 + v1, ss = v0 * v0 + v1 * v1;
#pragma unroll
    for (int o = 32; o > 0; o >>= 1) { s += __shfl_xor(s, o); ss += __shfl_xor(ss, o); }
    __shared__ float sb[8];
    int w = tid >> 6;
    if ((tid & 63) == 0) { sb[w] = s; sb[4 + w] = ss; }
    __syncthreads();
    s = sb[0] + sb[1] + sb[2] + sb[3];
    ss = sb[4] + sb[5] + sb[6] + sb[7];
    float mean = s * (1.f / D_);
    float var = ss * (1.f / D_) - mean * mean;
    float rstd = rsqrtf(var + 1e-5f);
#pragma unroll
    for (int p = 0; p < 2; p++) {
        int c = tid + p * 256;
        if (c >= D_) break;
        float v = (p ? v1 : v0);
        float o = (v - mean) * rstd * g[c] + b[c];
        size_t idx = (size_t)row * D_ + c;
        if (MODE == 0) outF[idx] = o;
        else {
            ushort hv = f2b(o);
            outH[idx] = hv;
            if (MODE == 2) outL[idx] = f2b(o - b2f(hv));
        }
    }
}

// ---------------- fused sel + LayerNorm ----------------
// h[row] += tw0*eod[p0] + tw1*eod[p1]; write h back; LN(h) -> outputs per MODE.
template<int MODE>
__global__ __launch_bounds__(256) void selln_k(float* __restrict__ h,
                                               const ushort* __restrict__ eodb,
                                               const float* __restrict__ tw,
                                               const int* __restrict__ tpos,
                                               const float* __restrict__ g, const float* __restrict__ b,
                                               float* __restrict__ outF,
                                               ushort* __restrict__ outH, ushort* __restrict__ outL)
{
    int row = blockIdx.x;
    int tid = threadIdx.x;
    float* hp = h + (size_t)row * D_;
    int p0 = tpos[row * 2], p1 = tpos[row * 2 + 1];
    float w0 = tw[row * 2], w1 = tw[row * 2 + 1];
    const ushort* e0 = eodb + (size_t)p0 * D_;
    const ushort* e1 = eodb + (size_t)p1 * D_;
    float v0 = hp[tid] + w0 * b2f(e0[tid]) + w1 * b2f(e1[tid]);
    float v1 = 0.f;
    if (tid < D_ - 256) v1 = hp[256 + tid] + w0 * b2f(e0[256 + tid]) + w1 * b2f(e1[256 + tid]);
    hp[tid] = v0;
    if (tid < D_ - 256) hp[256 + tid] = v1;
    float s = v0 + v1, ss = v0 * v0 + v1 * v1;
#pragma unroll
    for (int o = 32; o > 0; o >>= 1) { s += __shfl_xor(s, o); ss += __shfl_xor(ss, o); }
    __shared__ float sb[8];
    int w = tid >> 6;
    if ((tid & 63) == 0) { sb[w] = s; sb[4 + w] = ss; }
    __syncthreads();
    s = sb[0] + sb[1] + sb[2] + sb[3];
    ss = sb[4] + sb[5] + sb[6] + sb[7];
    float mean = s * (1.f / D_);
    float var = ss * (1.f / D_) - mean * mean;
    float rstd = rsqrtf(var + 1e-5f);
#pragma unroll
    for (int p = 0; p < 2; p++) {
        int c = tid + p * 256;
        if (c >= D_) break;
        float v = (p ? v1 : v0);
        float o = (v - mean) * rstd * g[c] + b[c];
        size_t idx = (size_t)row * D_ + c;
        if (MODE == 0) outF[idx] = o;
        else {
            ushort hv = f2b(o);
            outH[idx] = hv;
            if (MODE == 2) outL[idx] = f2b(o - b2f(hv));
        }
    }
}

// ---------------- bf16 MFMA GEMM, 64x64 tile, double-buffered LDS ----------------
// OM: 0 = f32 out, 1 = bf16 out, 2 = both, 3 = xp-special (bf16 col<nb16 + bcint scatter col>=24)
template<int OM, bool NG, bool KG, bool GATHER>
__global__ __launch_bounds__(256) void gemm_b(
    const ushort* __restrict__ A, int lda, long aOff,
    const ushort* __restrict__ W, int ldw, long wOff,
    float* __restrict__ C, int ldc, long cOff,
    ushort* __restrict__ Cb, int ldcb, long cbOff, int nb16,
    const float* __restrict__ bias, long bOff,
    const int* __restrict__ glist, const int* __restrict__ gcnt,
    int N, int K, int act, int acc)
{
    __shared__ __align__(16) ushort As[2][64 * PIT];
    __shared__ __align__(16) ushort Bs[2][64 * PIT];
    const int z = blockIdx.z;
    const int bm = blockIdx.y * 64, bn = blockIdx.x * 64;
    int cnt = 0;
    if (gcnt) { cnt = gcnt[z]; if (bm >= cnt) return; }
    const int tid = threadIdx.x, w = tid >> 6, lane = tid & 63;
    const int wm = (w >> 1) * 32, wn = (w & 1) * 32;
    const int l16 = lane & 15, lk = lane >> 4;
    const int r0 = tid >> 2, c0 = (tid & 3) * 8;
    const ushort* Ab;
    if (GATHER) {
        int gr = bm + r0;
        int t_idx = (gr < cnt) ? glist[(size_t)z * BT_ + gr] : 0;
        Ab = A + (size_t)t_idx * lda;
    } else {
        Ab = A + (size_t)z * aOff + (size_t)(bm + r0) * lda;
    }
    const ushort* Wb = W + (size_t)z * wOff;

    f32x4 accv[2][2];
#pragma unroll
    for (int i = 0; i < 2; i++)
#pragma unroll
        for (int j = 0; j < 2; j++) accv[i][j] = (f32x4)0.f;

    u16x8 arg;
    ushort wrg[8];
    auto LOADA = [&](int k0) {
        arg = *reinterpret_cast<const u16x8*>(Ab + k0 + c0);
    };
    auto LOADW = [&](int k0) {
#pragma unroll
        for (int i = 0; i < 8; i++) {
            int kk = k0 + w * 8 + i;
            bool ok = (!KG || kk < K) && (!NG || (bn + lane) < N);
            wrg[i] = ok ? Wb[(size_t)kk * ldw + bn + lane] : (ushort)0;
        }
    };
    auto STORE = [&](int buf) {
        *reinterpret_cast<u16x8*>(&As[buf][r0 * PIT + c0]) = arg;
        *reinterpret_cast<ushort4*>(&Bs[buf][lane * PIT + w * 8]) =
            make_ushort4(wrg[0], wrg[1], wrg[2], wrg[3]);
        *reinterpret_cast<ushort4*>(&Bs[buf][lane * PIT + w * 8 + 4]) =
            make_ushort4(wrg[4], wrg[5], wrg[6], wrg[7]);
    };

    LOADA(0); LOADW(0); STORE(0);
    __syncthreads();
    const int NIT = (K + 31) / 32;
    for (int it = 0; it < NIT; it++) {
        int cur = it & 1;
        bool more = (it + 1 < NIT);
        if (more) { LOADA((it + 1) * 32); LOADW((it + 1) * 32); }
        s8v af[2], bfr[2];
#pragma unroll
        for (int mf = 0; mf < 2; mf++)
            af[mf] = *reinterpret_cast<const s8v*>(&As[cur][(wm + mf * 16 + l16) * PIT + lk * 8]);
#pragma unroll
        for (int nf = 0; nf < 2; nf++)
            bfr[nf] = *reinterpret_cast<const s8v*>(&Bs[cur][(wn + nf * 16 + l16) * PIT + lk * 8]);
#pragma unroll
        for (int mf = 0; mf < 2; mf++)
#pragma unroll
            for (int nf = 0; nf < 2; nf++)
                accv[mf][nf] = __builtin_amdgcn_mfma_f32_16x16x32_bf16(af[mf], bfr[nf], accv[mf][nf], 0, 0, 0);
        if (more) { STORE(cur ^ 1); __syncthreads(); }
    }

    const float* biasb = bias ? bias + (size_t)z * bOff : nullptr;
#pragma unroll
    for (int mf = 0; mf < 2; mf++) {
#pragma unroll
        for (int nf = 0; nf < 2; nf++) {
            int col = bn + wn + nf * 16 + l16;
            if (NG && col >= N) continue;
#pragma unroll
            for (int r = 0; r < 4; r++) {
                int rr = bm + wm + mf * 16 + lk * 4 + r;
                if (gcnt && rr >= cnt) continue;
                float v = accv[mf][nf][r];
                if (biasb) v += biasb[col];
                if (act == 1) v = siluf(v);
                else if (act == 2) v = (v > 0.f) ? v + log1pf(__expf(-v)) : log1pf(__expf(v));
                if (OM == 0 || OM == 2) {
                    float* Cz = C + (size_t)z * cOff;
                    size_t ci = (size_t)rr * ldc + col;
                    Cz[ci] = acc ? (Cz[ci] + v) : v;
                }
                if (OM == 1 || OM == 2) {
                    if (col < nb16)
                        (Cb + (size_t)z * cbOff)[(size_t)rr * ldcb + col] = f2b(v);
                }
                if (OM == 3) {
                    if (col < nb16)
                        Cb[(size_t)rr * ldcb + col] = f2b(v);
                    if (col >= 24) {        // bcint scatter: {B[s],C[s]} interleaved
                        int q = col - 24;
                        C[(size_t)rr * 64 + ((q < 32) ? (2 * q) : (2 * (q - 32) + 1))] = v;
                    }
                }
            }
        }
    }
}

// ---------------- bf16x3 router GEMM (~f32 accuracy), regc fused into epilogue ----------------
__global__ __launch_bounds__(256) void gemm3_k(
    const ushort* __restrict__ Ah, const ushort* __restrict__ Al, int lda,
    const ushort* __restrict__ Wh, const ushort* __restrict__ Wl, int ldw,
    float* __restrict__ C,
    const float* __restrict__ bias,
    const float* __restrict__ regime, const float* __restrict__ rw1t,
    int N, int K)
{
    __shared__ __align__(16) ushort sAh[64 * PIT], sAl[64 * PIT];
    __shared__ __align__(16) ushort sWh[128 * PIT], sWl[128 * PIT];
    const int bm = blockIdx.y * 64, bn = blockIdx.x * 128;
    const int tid = threadIdx.x, w = tid >> 6, lane = tid & 63;
    const int wm = (w >> 1) * 32, wn = (w & 1) * 64;
    const int l16 = lane & 15, lk = lane >> 4;
    const int r0 = tid >> 2, c0 = (tid & 3) * 8;
    f32x4 accv[2][4];
#pragma unroll
    for (int i = 0; i < 2; i++)
#pragma unroll
        for (int j = 0; j < 4; j++) accv[i][j] = (f32x4)0.f;

    for (int k0 = 0; k0 < K; k0 += 32) {
        *reinterpret_cast<u16x8*>(&sAh[r0 * PIT + c0]) =
            *reinterpret_cast<const u16x8*>(Ah + (size_t)(bm + r0) * lda + k0 + c0);
        *reinterpret_cast<u16x8*>(&sAl[r0 * PIT + c0]) =
            *reinterpret_cast<const u16x8*>(Al + (size_t)(bm + r0) * lda + k0 + c0);
#pragma unroll
        for (int hh = 0; hh < 2; hh++) {
            int n = hh * 64 + lane;
            ushort th[8], tl[8];
#pragma unroll
            for (int i = 0; i < 8; i++) {
                int kk = k0 + w * 8 + i;
                th[i] = Wh[(size_t)kk * ldw + bn + n];
                tl[i] = Wl[(size_t)kk * ldw + bn + n];
            }
            *reinterpret_cast<ushort4*>(&sWh[n * PIT + w * 8])     = make_ushort4(th[0], th[1], th[2], th[3]);
            *reinterpret_cast<ushort4*>(&sWh[n * PIT + w * 8 + 4]) = make_ushort4(th[4], th[5], th[6], th[7]);
            *reinterpret_cast<ushort4*>(&sWl[n * PIT + w * 8])     = make_ushort4(tl[0], tl[1], tl[2], tl[3]);
            *reinterpret_cast<ushort4*>(&sWl[n * PIT + w * 8 + 4]) = make_ushort4(tl[4], tl[5], tl[6], tl[7]);
        }
        __syncthreads();
        s8v ah[2], al[2], bh[4], bl[4];
#pragma unroll
        for (int mf = 0; mf < 2; mf++) {
            ah[mf] = *reinterpret_cast<const s8v*>(&sAh[(wm + mf * 16 + l16) * PIT + lk * 8]);
            al[mf] = *reinterpret_cast<const s8v*>(&sAl[(wm + mf * 16 + l16) * PIT + lk * 8]);
        }
#pragma unroll
        for (int nf = 0; nf < 4; nf++) {
            bh[nf] = *reinterpret_cast<const s8v*>(&sWh[(wn + nf * 16 + l16) * PIT + lk * 8]);
            bl[nf] = *reinterpret_cast<const s8v*>(&sWl[(wn + nf * 16 + l16) * PIT + lk * 8]);
        }
#pragma unroll
        for (int mf = 0; mf < 2; mf++)
#pragma unroll
            for (int nf = 0; nf < 4; nf++) {
                accv[mf][nf] = __builtin_amdgcn_mfma_f32_16x16x32_bf16(ah[mf], bh[nf], accv[mf][nf], 0, 0, 0);
                accv[mf][nf] = __builtin_amdgcn_mfma_f32_16x16x32_bf16(ah[mf], bl[nf], accv[mf][nf], 0, 0, 0);
                accv[mf][nf] = __builtin_amdgcn_mfma_f32_16x16x32_bf16(al[mf], bh[nf], accv[mf][nf], 0, 0, 0);
            }
        __syncthreads();
    }
    const float* rg = regime + (bm / T_) * R_;
#pragma unroll
    for (int mf = 0; mf < 2; mf++)
#pragma unroll
        for (int nf = 0; nf < 4; nf++) {
            int col = bn + wn + nf * 16 + l16;
            float rb = 0.f;
#pragma unroll
            for (int r = 0; r < R_; r++) rb += rg[r] * rw1t[r * D_ + col];
#pragma unroll
            for (int r = 0; r < 4; r++) {
                int rr = bm + wm + mf * 16 + lk * 4 + r;
                float v = accv[mf][nf][r] + bias[col] + rb;
                C[(size_t)rr * N + col] = siluf(v);
            }
        }
}

// ---------------- SSM scan v4: b64-packed operands, XCD-swizzled ----------------
// DS ops/step/lane: 1 b64 sdx (broadcast) + 1 b64 sbc (2-way free) + 1 b32 sacc write
// (+1 b32 amortized reduce-read). z read from global (L2). LDS 53248 B = 3 blocks/CU.
__global__ __launch_bounds__(128) void scan_k(
    const float* __restrict__ dtb, const float* __restrict__ xz, const float* __restrict__ bcint,
    const float* __restrict__ alr, const float* __restrict__ aim, const float* __restrict__ dvecp,
    ushort* __restrict__ ygb)
{
    int p = blockIdx.x;
    int blk = (p & 7) * 96 + (p >> 3);       // 768 = 8*96, bijective XCD clustering
    int b = blk / 192;
    int dbase = (blk % 192) * 4;
    int tid = threadIdx.x;                   // 0..127
    int ch = tid >> 5;                       // 0..3
    int s = tid & 31;
    int d = dbase + ch;
    __shared__ __align__(16) float sdx[64 * SPD];     // [t][{dt,x}x4ch]  2.5 KB
    __shared__ __align__(16) float sbc[64 * SPB];     // [t][{B,C}x32s]  16.5 KB
    __shared__ float sacc[SCH * 4][33];               // 33.8 KB
    float negA = -__expf(alr[d * S_ + s]);
    float aimv = aim[d * S_ + s];
    float4 dv4 = *reinterpret_cast<const float4*>(dvecp + dbase);
    float dvc[4] = {dv4.x, dv4.y, dv4.z, dv4.w};
    float hre = 0.f, him = 0.f;
    const float* dtp = dtb + (size_t)b * T_ * DI_;
    const float* xzp = xz + (size_t)b * T_ * (2 * DI_);
    const float* bcp = bcint + (size_t)b * T_ * 64;
    ushort* ygp = ygb + (size_t)b * T_ * DI_;

    for (int c = 0; c < T_ / SCH; c++) {
        int tc = c * SCH;
        __syncthreads();
        if (tid < 64) {
            int t = tid;
            float4 d4 = *reinterpret_cast<const float4*>(dtp + (size_t)(tc + t) * DI_ + dbase);
            float4 x4 = *reinterpret_cast<const float4*>(xzp + (size_t)(tc + t) * (2 * DI_) + dbase);
            float dd[4] = {d4.x, d4.y, d4.z, d4.w};
            float xx[4] = {x4.x, x4.y, x4.z, x4.w};
#pragma unroll
            for (int k = 0; k < 4; k++)
                *reinterpret_cast<float2*>(&sdx[t * SPD + 2 * k]) = make_float2(dd[k], xx[k]);
        }
#pragma unroll
        for (int i = 0; i < 8; i++) {
            int idx = tid + i * 128;         // 1024 float4 over 64 rows x 16
            int tt = idx >> 4, q = idx & 15;
            *reinterpret_cast<float4*>(&sbc[tt * SPB + 4 * q]) =
                *reinterpret_cast<const float4*>(bcp + (size_t)(tc + tt) * 64 + 4 * q);
        }
        __syncthreads();

        const float* dxr = &sdx[2 * ch];
        const float* bcr = &sbc[2 * s];
        float2 dx0 = *reinterpret_cast<const float2*>(dxr);
        float2 bc0 = *reinterpret_cast<const float2*>(bcr);
        float2 dx1 = *reinterpret_cast<const float2*>(dxr + SPD);
        float2 bc1 = *reinterpret_cast<const float2*>(bcr + SPB);
#pragma unroll 4
        for (int t = 0; t < SCH; t++) {
            float2 dx2 = make_float2(0.f, 0.f), bc2 = dx2;
            if (t + 2 < SCH) {
                dx2 = *reinterpret_cast<const float2*>(dxr + (t + 2) * SPD);
                bc2 = *reinterpret_cast<const float2*>(bcr + (t + 2) * SPB);
            }
            float e = __expf(negA * dx0.x);
            float sn, cs;
            __sincosf(aimv * dx0.x, &sn, &cs);
            float dre = e * cs, dim = e * sn;
            float u = dx0.x * dx0.y * bc0.x;
            float nre = fmaf(dre, hre, fmaf(-dim, him, u));
            him = fmaf(dre, him, dim * hre);
            hre = nre;
            sacc[t * 4 + ch][s] = hre * bc0.y;
            dx0 = dx1; bc0 = bc1; dx1 = dx2; bc1 = bc2;
        }
        __syncthreads();

#pragma unroll
        for (int p2 = 0; p2 < 2; p2++) {
            int r = tid + p2 * 128;
            int t = r >> 2, cch = r & 3;
            float acc = 0.f;
#pragma unroll
            for (int s2 = 0; s2 < 32; s2++) acc += sacc[r][s2];
            float xv = sdx[t * SPD + 2 * cch + 1];
            float zv = xzp[(size_t)(tc + t) * (2 * DI_) + DI_ + dbase + cch];
            float y = (acc + dvc[cch] * xv) * siluf(zv);
            ygp[(size_t)(tc + t) * DI_ + dbase + cch] = f2b(y);
        }
    }
}

// ---------------- gate logits ----------------
__global__ __launch_bounds__(256) void gl_k(const float* __restrict__ hmid,
                                            const float* __restrict__ rw2l,
                                            const float* __restrict__ rb2l, float* __restrict__ gl)
{
    int pid = blockIdx.x * 16 + (threadIdx.x >> 4);
    int li = threadIdx.x & 15;
    int t = pid / E_, e = pid - t * E_;
    const float* hp = hmid + (size_t)t * D_;
    float a = 0.f;
#pragma unroll 4
    for (int j = 0; j < D_ / 16; j++) {
        int k = li + j * 16;
        a += hp[k] * rw2l[k * E_ + e];
    }
#pragma unroll
    for (int o = 8; o > 0; o >>= 1) a += __shfl_xor(a, o, 16);
    if (li == 0) gl[t * E_ + e] = a + rb2l[e];
}

// ---------------- fused router + assign (single block) ----------------
__global__ __launch_bounds__(1024) void router_assign_k(const float* __restrict__ gl,
                                                        float* __restrict__ tw,
                                                        int* __restrict__ glist,
                                                        int* __restrict__ tpos,
                                                        int* __restrict__ cnt,
                                                        float* __restrict__ statL)
{
    __shared__ float s_p[E_], s_c[E_];
    __shared__ int scnt[E_];
    int tid = threadIdx.x;
    if (tid < E_) { s_p[tid] = 0.f; s_c[tid] = 0.f; scnt[tid] = 0; }
    __syncthreads();
    for (int t = tid; t < BT_; t += 1024) {
        float g[E_];
        for (int e = 0; e < E_; e++) g[e] = gl[t * E_ + e];
        int i0 = 0; float v0 = g[0];
        for (int e = 1; e < E_; e++) if (g[e] > v0) { v0 = g[e]; i0 = e; }
        int i1 = -1; float v1 = -1e30f;
        for (int e = 0; e < E_; e++) if (e != i0 && g[e] > v1) { v1 = g[e]; i1 = e; }
        float e1 = __expf(v1 - v0);
        float inv = 1.f / (1.f + e1);
        tw[t * 2] = inv; tw[t * 2 + 1] = e1 * inv;
        int pos0 = atomicAdd(&scnt[i0], 1);
        glist[i0 * BT_ + pos0] = t;
        tpos[2 * t] = i0 * BT_ + pos0;
        int pos1 = atomicAdd(&scnt[i1], 1);
        glist[i1 * BT_ + pos1] = t;
        tpos[2 * t + 1] = i1 * BT_ + pos1;
        float pb[E_], se = 0.f;
        for (int e = 0; e < E_; e++) { pb[e] = __expf(g[e] - v0); se += pb[e]; }
        float rse = 1.f / se;
        for (int e = 0; e < E_; e++) atomicAdd(&s_p[e], pb[e] * rse);
        atomicAdd(&s_c[i0], 1.f);
    }
    __syncthreads();
    if (tid < E_) {
        cnt[tid] = scnt[tid];
        statL[tid] = s_p[tid];
        statL[8 + tid] = s_c[tid];
    }
}

__global__ void write_aux_k(const float* __restrict__ stats, float* __restrict__ out)
{
    if (threadIdx.x == 0 && blockIdx.x == 0) {
        float aux = 0.f;
        for (int l = 0; l < L_; l++) {
            float s = 0.f;
            for (int e = 0; e < E_; e++) s += stats[l * 16 + e] * stats[l * 16 + 8 + e];
            aux += 0.01f * (float)E_ * s / ((float)BT_ * (float)BT_);
        }
        out[BT_ * D_] = aux;
    }
}

// ---------------- launch ----------------
extern "C" void kernel_launch(void* const* d_in, const int* in_sizes, int n_in,
                              void* d_out, int out_size, void* d_ws, size_t ws_size,
                              hipStream_t stream)
{
    const float* x       = (const float*)d_in[0];
    const float* regime  = (const float*)d_in[1];
    const float* film_w1 = (const float*)d_in[2];
    const float* film_b1 = (const float*)d_in[3];
    const float* film_w2 = (const float*)d_in[4];
    const float* film_b2 = (const float*)d_in[5];
    const float* ssm_ng  = (const float*)d_in[6];
    const float* ssm_nb  = (const float*)d_in[7];
    const float* in_w    = (const float*)d_in[8];
    const float* xp_w    = (const float*)d_in[9];
    const float* dt_w    = (const float*)d_in[10];
    const float* dt_b    = (const float*)d_in[11];
    const float* alr     = (const float*)d_in[12];
    const float* aimp    = (const float*)d_in[13];
    const float* ssm_d   = (const float*)d_in[14];
    const float* out_w   = (const float*)d_in[15];
    const float* moe_ng  = (const float*)d_in[16];
    const float* moe_nb  = (const float*)d_in[17];
    const float* r_w1    = (const float*)d_in[18];
    const float* r_b1    = (const float*)d_in[19];
    const float* r_w2    = (const float*)d_in[20];
    const float* r_b2    = (const float*)d_in[21];
    const float* e_w1    = (const float*)d_in[22];
    const float* e_b1    = (const float*)d_in[23];
    const float* e_w2    = (const float*)d_in[24];
    const float* e_b2    = (const float*)d_in[25];
    const float* fin_g   = (const float*)d_in[26];
    const float* fin_b   = (const float*)d_in[27];

    float* ws = (float*)d_ws;
    size_t o = 0;
    float*  h      = ws + o; o += 786432;
    float*  stats  = ws + o; o += 64;
    ushort* xnH    = (ushort*)(ws + o); o += 393216;
    ushort* xnL    = (ushort*)(ws + o); o += 393216;
    float*  gl     = ws + o; o += 12288;
    float*  tw     = ws + o; o += 4096;
    int*    glist  = (int*)(ws + o); o += 12288;
    int*    tpos   = (int*)(ws + o); o += 4096;
    int*    cnt    = (int*)(ws + o); o += 16;
    ushort* in_wb  = (ushort*)(ws + o); o += 589824;
    ushort* xp_wb  = (ushort*)(ws + o); o += 67584;
    ushort* dt_wb  = (ushort*)(ws + o); o += 18432;
    ushort* out_wb = (ushort*)(ws + o); o += 294912;
    ushort* e1b    = (ushort*)(ws + o); o += 1179648;
    ushort* e2b    = (ushort*)(ws + o); o += 1179648;
    ushort* r1h    = (ushort*)(ws + o); o += 147456;
    ushort* r1l    = (ushort*)(ws + o); o += 147456;
    // phase-aliased pool (SSM scratch / MoE scratch)
    float*  xz    = ws + o;                            // 3145728 w
    ushort* xzb   = (ushort*)(ws + o + 3145728);       // 786432 w
    float*  bcint = ws + o + 3932160;                  // 131072 w  [2048][64] {B,C} interleaved
    ushort* xdblb = (ushort*)(ws + o + 4063232);       // 32768 w
    float*  dtb   = ws + o + 4096000;                  // 1572864 w
    ushort* ygb   = (ushort*)(ws + o + 5668864);       // 786432 w -> SSM pool ends o+6455296
    float*  hmid  = ws + o;                            // aliases xz (MoE phase)
    ushort* eohb  = (ushort*)(ws + o + 786432);        // [6][2048][512] bf16
    ushort* eodb  = (ushort*)(ws + o + 3932160);       // [6][2048][384] bf16
    float*  gb    = ws + o;                            // film temp (pool, pre-loop)

    conv_k<<<2048, 256, 0, stream>>>(in_w, xp_w, dt_w, out_w, e_w1, e_w2, r_w1,
                                     in_wb, xp_wb, dt_wb, out_wb, e1b, e2b, r1h, r1l);
    film_k<<<B_, 2 * D_, 0, stream>>>(regime, film_w1, film_b1, film_w2, film_b2, gb, stats);
    film_apply_k<<<(B_ * T_ * D_ + 255) / 256, 256, 0, stream>>>(x, gb, h);

    for (int l = 0; l < L_; l++) {
        // ---- SSM block ----
        if (l == 0)
            ln_k<1><<<BT_, 256, 0, stream>>>(h, ssm_ng, ssm_nb, nullptr, xnH, nullptr);
        // (for l>0, xnH was produced by selln_k<1> at the end of the previous MoE block)
        gemm_b<2, false, false, false><<<dim3(24, 32), 256, 0, stream>>>(
            xnH, D_, 0, in_wb + (size_t)l * 589824, 2 * DI_, 0,
            xz, 2 * DI_, 0, xzb, DI_, 0, DI_,
            nullptr, 0, nullptr, nullptr, 2 * DI_, D_, 0, 0);
        gemm_b<3, true, false, false><<<dim3(2, 32), 256, 0, stream>>>(
            xzb, DI_, 0, xp_wb + (size_t)l * 67584, XPN_, 0,
            bcint, 64, 0, xdblb, 32, 0, 32,
            nullptr, 0, nullptr, nullptr, XPN_, DI_, 0, 0);
        gemm_b<0, false, true, false><<<dim3(12, 32), 256, 0, stream>>>(
            xdblb, 32, 0, dt_wb + (size_t)l * 18432, DI_, 0,
            dtb, DI_, 0, nullptr, 0, 0, 0,
            dt_b + l * DI_, 0, nullptr, nullptr, DI_, DTR_, 2, 0);
        scan_k<<<B_ * 192, 128, 0, stream>>>(
            dtb, xz, bcint, alr + (size_t)l * DI_ * S_, aimp + (size_t)l * DI_ * S_,
            ssm_d + l * DI_, ygb);
        gemm_b<0, false, false, false><<<dim3(6, 32), 256, 0, stream>>>(
            ygb, DI_, 0, out_wb + (size_t)l * 294912, D_, 0,
            h, D_, 0, nullptr, 0, 0, 0,
            nullptr, 0, nullptr, nullptr, D_, DI_, 0, 1);

        // ---- MoE block ----
        ln_k<2><<<BT_, 256, 0, stream>>>(h, moe_ng + l * D_, moe_nb + l * D_, nullptr, xnH, xnL);
        gemm3_k<<<dim3(3, 32), 256, 0, stream>>>(
            xnH, xnL, D_, r1h + (size_t)l * 147456, r1l + (size_t)l * 147456, D_,
            hmid, r_b1 + l * D_,
            regime, r_w1 + (size_t)l * ((D_ + R_) * D_) + (size_t)D_ * D_,
            D_, D_);
        gl_k<<<BT_ * E_ / 16, 256, 0, stream>>>(hmid, r_w2 + (size_t)l * D_ * E_, r_b2 + l * E_, gl);
        router_assign_k<<<1, 1024, 0, stream>>>(gl, tw, glist, tpos, cnt, stats + l * 16);
        gemm_b<1, false, false, true><<<dim3(8, 32, 6), 256, 0, stream>>>(
            xnH, D_, 0, e1b + (size_t)l * 1179648, H_, (long)D_ * H_,
            nullptr, 0, 0, eohb, H_, (long)BT_ * H_, H_,
            e_b1 + (size_t)l * E_ * H_, H_, glist, cnt, H_, D_, 1, 0);
        gemm_b<1, false, false, false><<<dim3(6, 32, 6), 256, 0, stream>>>(
            eohb, H_, (long)BT_ * H_, e2b + (size_t)l * 1179648, D_, (long)H_ * D_,
            nullptr, 0, 0, eodb, D_, (long)BT_ * D_, D_,
            e_b2 + (size_t)l * E_ * D_, D_, nullptr, cnt, D_, H_, 0, 0);
        // fused expert-combine + LayerNorm (next SSM ln, or final ln -> d_out)
        if (l < L_ - 1)
            selln_k<1><<<BT_, 256, 0, stream>>>(h, eodb, tw, tpos,
                ssm_ng + (l + 1) * D_, ssm_nb + (l + 1) * D_, nullptr, xnH, nullptr);
        else
            selln_k<0><<<BT_, 256, 0, stream>>>(h, eodb, tw, tpos,
                fin_g, fin_b, (float*)d_out, nullptr, nullptr);
    }

    write_aux_k<<<1, 64, 0, stream>>>(stats, (float*)d_out);
}

// Round 13
// 489.574 us; speedup vs baseline: 1.2512x; 1.2512x over previous
//
#include <hip/hip_runtime.h>
#include <hip/hip_bf16.h>
#include <math.h>

#define B_   4
#define T_   512
#define D_   384
#define S_   32
#define E_   6
#define H_   512
#define R_   5
#define L_   2
#define DI_  768
#define DTR_ 24
#define BT_  2048
#define XPN_ 88   // DTR + 2*S
#define SCH  64   // scan time-chunk
#define PIT  40   // GEMM LDS row pitch in ushorts (80 B)
#define SPD  10   // scan sdx pitch (floats): [t][{dt,x}x4ch]
#define SPB  66   // scan sbc pitch (floats): [t][{B,C}x32s]

typedef short s8v __attribute__((ext_vector_type(8)));
typedef float f32x4 __attribute__((ext_vector_type(4)));
typedef ushort u16x8 __attribute__((ext_vector_type(8)));

__device__ __forceinline__ float siluf(float x) { return x / (1.f + __expf(-x)); }
__device__ __forceinline__ ushort f2b(float f) {
    unsigned u = __float_as_uint(f);
    return (ushort)((u + 0x7FFFu + ((u >> 16) & 1u)) >> 16);
}
__device__ __forceinline__ float b2f(ushort h) { return __uint_as_float(((unsigned)h) << 16); }

// ---------------- weight pre-conversion ----------------
#define CN0 1179648L  // in_w
#define CN1 135168L   // xp_w
#define CN2 36864L    // dt_w (unused after dt-fusion; kept to avoid layout churn)
#define CN3 589824L   // out_w
#define CN4 2359296L  // e_w1
#define CN5 2359296L  // e_w2
#define CN6 294912L   // r_w1[:384,:] hi/lo (2 layers)
__global__ void conv_k(const float* __restrict__ in_w, const float* __restrict__ xp_w,
                       const float* __restrict__ dt_w, const float* __restrict__ out_w,
                       const float* __restrict__ e_w1, const float* __restrict__ e_w2,
                       const float* __restrict__ r_w1,
                       ushort* __restrict__ in_wb, ushort* __restrict__ xp_wb,
                       ushort* __restrict__ dt_wb, ushort* __restrict__ out_wb,
                       ushort* __restrict__ e1b, ushort* __restrict__ e2b,
                       ushort* __restrict__ r1h, ushort* __restrict__ r1l)
{
    const long total = CN0 + CN1 + CN2 + CN3 + CN4 + CN5 + CN6;
    long stride = (long)gridDim.x * 256;
    for (long i = (long)blockIdx.x * 256 + threadIdx.x; i < total; i += stride) {
        long j = i;
        if (j < CN0) { in_wb[j] = f2b(in_w[j]); continue; }
        j -= CN0;
        if (j < CN1) { xp_wb[j] = f2b(xp_w[j]); continue; }
        j -= CN1;
        if (j < CN2) { dt_wb[j] = f2b(dt_w[j]); continue; }
        j -= CN2;
        if (j < CN3) { out_wb[j] = f2b(out_w[j]); continue; }
        j -= CN3;
        if (j < CN4) { e1b[j] = f2b(e_w1[j]); continue; }
        j -= CN4;
        if (j < CN5) { e2b[j] = f2b(e_w2[j]); continue; }
        j -= CN5;
        {
            long l = j / 147456, rem = j - l * 147456;
            float v = r_w1[l * (long)((D_ + R_) * D_) + rem];
            ushort hv = f2b(v);
            r1h[j] = hv;
            r1l[j] = f2b(v - b2f(hv));
        }
    }
}

// ---------------- FiLM ----------------
__global__ void film_k(const float* __restrict__ regime, const float* __restrict__ w1,
                       const float* __restrict__ b1, const float* __restrict__ w2,
                       const float* __restrict__ b2, float* __restrict__ gb,
                       float* __restrict__ stats)
{
    int b = blockIdx.x;
    int tid = threadIdx.x;
    if (b == 0 && tid < 40) stats[tid] = 0.f;
    __shared__ float t1[D_];
    if (tid < D_) {
        float a = b1[tid];
        for (int r = 0; r < R_; r++) a += regime[b * R_ + r] * w1[r * D_ + tid];
        t1[tid] = siluf(a);
    }
    __syncthreads();
    float a = b2[tid];
    for (int d = 0; d < D_; d++) a += t1[d] * w2[d * (2 * D_) + tid];
    gb[b * (2 * D_) + tid] = a;
}

__global__ void film_apply_k(const float* __restrict__ x, const float* __restrict__ gb,
                             float* __restrict__ h)
{
    int i = blockIdx.x * 256 + threadIdx.x;
    if (i >= B_ * T_ * D_) return;
    int b = i / (T_ * D_);
    int d = i % D_;
    h[i] = x[i] * (1.f + gb[b * (2 * D_) + d]) + gb[b * (2 * D_) + D_ + d];
}

// ---------------- LayerNorm: MODE 0 = f32 out, 1 = bf16 out, 2 = bf16 hi+lo ----------------
template<int MODE>
__global__ __launch_bounds__(256) void ln_k(const float* __restrict__ in,
                                            const float* __restrict__ g, const float* __restrict__ b,
                                            float* __restrict__ outF,
                                            ushort* __restrict__ outH, ushort* __restrict__ outL)
{
    int row = blockIdx.x;
    int tid = threadIdx.x;
    const float* x = in + (size_t)row * D_;
    float v0 = x[tid];
    float v1 = (tid < D_ - 256) ? x[256 + tid] : 0.f;
    float s = v0 + v1, ss = v0 * v0 + v1 * v1;
#pragma unroll
    for (int o = 32; o > 0; o >>= 1) { s += __shfl_xor(s, o); ss += __shfl_xor(ss, o); }
    __shared__ float sb[8];
    int w = tid >> 6;
    if ((tid & 63) == 0) { sb[w] = s; sb[4 + w] = ss; }
    __syncthreads();
    s = sb[0] + sb[1] + sb[2] + sb[3];
    ss = sb[4] + sb[5] + sb[6] + sb[7];
    float mean = s * (1.f / D_);
    float var = ss * (1.f / D_) - mean * mean;
    float rstd = rsqrtf(var + 1e-5f);
#pragma unroll
    for (int p = 0; p < 2; p++) {
        int c = tid + p * 256;
        if (c >= D_) break;
        float v = (p ? v1 : v0);
        float o = (v - mean) * rstd * g[c] + b[c];
        size_t idx = (size_t)row * D_ + c;
        if (MODE == 0) outF[idx] = o;
        else {
            ushort hv = f2b(o);
            outH[idx] = hv;
            if (MODE == 2) outL[idx] = f2b(o - b2f(hv));
        }
    }
}

// ---------------- fused sel + LayerNorm ----------------
template<int MODE>
__global__ __launch_bounds__(256) void selln_k(float* __restrict__ h,
                                               const ushort* __restrict__ eodb,
                                               const float* __restrict__ tw,
                                               const int* __restrict__ tpos,
                                               const float* __restrict__ g, const float* __restrict__ b,
                                               float* __restrict__ outF,
                                               ushort* __restrict__ outH, ushort* __restrict__ outL)
{
    int row = blockIdx.x;
    int tid = threadIdx.x;
    float* hp = h + (size_t)row * D_;
    int p0 = tpos[row * 2], p1 = tpos[row * 2 + 1];
    float w0 = tw[row * 2], w1 = tw[row * 2 + 1];
    const ushort* e0 = eodb + (size_t)p0 * D_;
    const ushort* e1 = eodb + (size_t)p1 * D_;
    float v0 = hp[tid] + w0 * b2f(e0[tid]) + w1 * b2f(e1[tid]);
    float v1 = 0.f;
    if (tid < D_ - 256) v1 = hp[256 + tid] + w0 * b2f(e0[256 + tid]) + w1 * b2f(e1[256 + tid]);
    hp[tid] = v0;
    if (tid < D_ - 256) hp[256 + tid] = v1;
    float s = v0 + v1, ss = v0 * v0 + v1 * v1;
#pragma unroll
    for (int o = 32; o > 0; o >>= 1) { s += __shfl_xor(s, o); ss += __shfl_xor(ss, o); }
    __shared__ float sb[8];
    int w = tid >> 6;
    if ((tid & 63) == 0) { sb[w] = s; sb[4 + w] = ss; }
    __syncthreads();
    s = sb[0] + sb[1] + sb[2] + sb[3];
    ss = sb[4] + sb[5] + sb[6] + sb[7];
    float mean = s * (1.f / D_);
    float var = ss * (1.f / D_) - mean * mean;
    float rstd = rsqrtf(var + 1e-5f);
#pragma unroll
    for (int p = 0; p < 2; p++) {
        int c = tid + p * 256;
        if (c >= D_) break;
        float v = (p ? v1 : v0);
        float o = (v - mean) * rstd * g[c] + b[c];
        size_t idx = (size_t)row * D_ + c;
        if (MODE == 0) outF[idx] = o;
        else {
            ushort hv = f2b(o);
            outH[idx] = hv;
            if (MODE == 2) outL[idx] = f2b(o - b2f(hv));
        }
    }
}

// ---------------- bf16 MFMA GEMM, 64x64 tile, double-buffered LDS ----------------
// OM: 0 = f32 out, 1 = bf16 out, 2 = both, 3 = xp-special (bf16 col<nb16 + bcint scatter col>=24)
template<int OM, bool NG, bool KG, bool GATHER>
__global__ __launch_bounds__(256) void gemm_b(
    const ushort* __restrict__ A, int lda, long aOff,
    const ushort* __restrict__ W, int ldw, long wOff,
    float* __restrict__ C, int ldc, long cOff,
    ushort* __restrict__ Cb, int ldcb, long cbOff, int nb16,
    const float* __restrict__ bias, long bOff,
    const int* __restrict__ glist, const int* __restrict__ gcnt,
    int N, int K, int act, int acc)
{
    __shared__ __align__(16) ushort As[2][64 * PIT];
    __shared__ __align__(16) ushort Bs[2][64 * PIT];
    const int z = blockIdx.z;
    const int bm = blockIdx.y * 64, bn = blockIdx.x * 64;
    int cnt = 0;
    if (gcnt) { cnt = gcnt[z]; if (bm >= cnt) return; }
    const int tid = threadIdx.x, w = tid >> 6, lane = tid & 63;
    const int wm = (w >> 1) * 32, wn = (w & 1) * 32;
    const int l16 = lane & 15, lk = lane >> 4;
    const int r0 = tid >> 2, c0 = (tid & 3) * 8;
    const ushort* Ab;
    if (GATHER) {
        int gr = bm + r0;
        int t_idx = (gr < cnt) ? glist[(size_t)z * BT_ + gr] : 0;
        Ab = A + (size_t)t_idx * lda;
    } else {
        Ab = A + (size_t)z * aOff + (size_t)(bm + r0) * lda;
    }
    const ushort* Wb = W + (size_t)z * wOff;

    f32x4 accv[2][2];
#pragma unroll
    for (int i = 0; i < 2; i++)
#pragma unroll
        for (int j = 0; j < 2; j++) accv[i][j] = (f32x4)0.f;

    u16x8 arg;
    ushort wrg[8];
    auto LOADA = [&](int k0) {
        arg = *reinterpret_cast<const u16x8*>(Ab + k0 + c0);
    };
    auto LOADW = [&](int k0) {
#pragma unroll
        for (int i = 0; i < 8; i++) {
            int kk = k0 + w * 8 + i;
            bool ok = (!KG || kk < K) && (!NG || (bn + lane) < N);
            wrg[i] = ok ? Wb[(size_t)kk * ldw + bn + lane] : (ushort)0;
        }
    };
    auto STORE = [&](int buf) {
        *reinterpret_cast<u16x8*>(&As[buf][r0 * PIT + c0]) = arg;
        *reinterpret_cast<ushort4*>(&Bs[buf][lane * PIT + w * 8]) =
            make_ushort4(wrg[0], wrg[1], wrg[2], wrg[3]);
        *reinterpret_cast<ushort4*>(&Bs[buf][lane * PIT + w * 8 + 4]) =
            make_ushort4(wrg[4], wrg[5], wrg[6], wrg[7]);
    };

    LOADA(0); LOADW(0); STORE(0);
    __syncthreads();
    const int NIT = (K + 31) / 32;
    for (int it = 0; it < NIT; it++) {
        int cur = it & 1;
        bool more = (it + 1 < NIT);
        if (more) { LOADA((it + 1) * 32); LOADW((it + 1) * 32); }
        s8v af[2], bfr[2];
#pragma unroll
        for (int mf = 0; mf < 2; mf++)
            af[mf] = *reinterpret_cast<const s8v*>(&As[cur][(wm + mf * 16 + l16) * PIT + lk * 8]);
#pragma unroll
        for (int nf = 0; nf < 2; nf++)
            bfr[nf] = *reinterpret_cast<const s8v*>(&Bs[cur][(wn + nf * 16 + l16) * PIT + lk * 8]);
#pragma unroll
        for (int mf = 0; mf < 2; mf++)
#pragma unroll
            for (int nf = 0; nf < 2; nf++)
                accv[mf][nf] = __builtin_amdgcn_mfma_f32_16x16x32_bf16(af[mf], bfr[nf], accv[mf][nf], 0, 0, 0);
        if (more) { STORE(cur ^ 1); __syncthreads(); }
    }

    const float* biasb = bias ? bias + (size_t)z * bOff : nullptr;
#pragma unroll
    for (int mf = 0; mf < 2; mf++) {
#pragma unroll
        for (int nf = 0; nf < 2; nf++) {
            int col = bn + wn + nf * 16 + l16;
            if (NG && col >= N) continue;
#pragma unroll
            for (int r = 0; r < 4; r++) {
                int rr = bm + wm + mf * 16 + lk * 4 + r;
                if (gcnt && rr >= cnt) continue;
                float v = accv[mf][nf][r];
                if (biasb) v += biasb[col];
                if (act == 1) v = siluf(v);
                else if (act == 2) v = (v > 0.f) ? v + log1pf(__expf(-v)) : log1pf(__expf(v));
                if (OM == 0 || OM == 2) {
                    float* Cz = C + (size_t)z * cOff;
                    size_t ci = (size_t)rr * ldc + col;
                    Cz[ci] = acc ? (Cz[ci] + v) : v;
                }
                if (OM == 1 || OM == 2) {
                    if (col < nb16)
                        (Cb + (size_t)z * cbOff)[(size_t)rr * ldcb + col] = f2b(v);
                }
                if (OM == 3) {
                    if (col < nb16)
                        Cb[(size_t)rr * ldcb + col] = f2b(v);
                    if (col >= 24) {        // bcint scatter: {B[s],C[s]} interleaved
                        int q = col - 24;
                        C[(size_t)rr * 64 + ((q < 32) ? (2 * q) : (2 * (q - 32) + 1))] = v;
                    }
                }
            }
        }
    }
}

// ---------------- bf16x3 router GEMM (~f32 accuracy), regc fused into epilogue ----------------
__global__ __launch_bounds__(256) void gemm3_k(
    const ushort* __restrict__ Ah, const ushort* __restrict__ Al, int lda,
    const ushort* __restrict__ Wh, const ushort* __restrict__ Wl, int ldw,
    float* __restrict__ C,
    const float* __restrict__ bias,
    const float* __restrict__ regime, const float* __restrict__ rw1t,
    int N, int K)
{
    __shared__ __align__(16) ushort sAh[64 * PIT], sAl[64 * PIT];
    __shared__ __align__(16) ushort sWh[128 * PIT], sWl[128 * PIT];
    const int bm = blockIdx.y * 64, bn = blockIdx.x * 128;
    const int tid = threadIdx.x, w = tid >> 6, lane = tid & 63;
    const int wm = (w >> 1) * 32, wn = (w & 1) * 64;
    const int l16 = lane & 15, lk = lane >> 4;
    const int r0 = tid >> 2, c0 = (tid & 3) * 8;
    f32x4 accv[2][4];
#pragma unroll
    for (int i = 0; i < 2; i++)
#pragma unroll
        for (int j = 0; j < 4; j++) accv[i][j] = (f32x4)0.f;

    for (int k0 = 0; k0 < K; k0 += 32) {
        *reinterpret_cast<u16x8*>(&sAh[r0 * PIT + c0]) =
            *reinterpret_cast<const u16x8*>(Ah + (size_t)(bm + r0) * lda + k0 + c0);
        *reinterpret_cast<u16x8*>(&sAl[r0 * PIT + c0]) =
            *reinterpret_cast<const u16x8*>(Al + (size_t)(bm + r0) * lda + k0 + c0);
#pragma unroll
        for (int hh = 0; hh < 2; hh++) {
            int n = hh * 64 + lane;
            ushort th[8], tl[8];
#pragma unroll
            for (int i = 0; i < 8; i++) {
                int kk = k0 + w * 8 + i;
                th[i] = Wh[(size_t)kk * ldw + bn + n];
                tl[i] = Wl[(size_t)kk * ldw + bn + n];
            }
            *reinterpret_cast<ushort4*>(&sWh[n * PIT + w * 8])     = make_ushort4(th[0], th[1], th[2], th[3]);
            *reinterpret_cast<ushort4*>(&sWh[n * PIT + w * 8 + 4]) = make_ushort4(th[4], th[5], th[6], th[7]);
            *reinterpret_cast<ushort4*>(&sWl[n * PIT + w * 8])     = make_ushort4(tl[0], tl[1], tl[2], tl[3]);
            *reinterpret_cast<ushort4*>(&sWl[n * PIT + w * 8 + 4]) = make_ushort4(tl[4], tl[5], tl[6], tl[7]);
        }
        __syncthreads();
        s8v ah[2], al[2], bh[4], bl[4];
#pragma unroll
        for (int mf = 0; mf < 2; mf++) {
            ah[mf] = *reinterpret_cast<const s8v*>(&sAh[(wm + mf * 16 + l16) * PIT + lk * 8]);
            al[mf] = *reinterpret_cast<const s8v*>(&sAl[(wm + mf * 16 + l16) * PIT + lk * 8]);
        }
#pragma unroll
        for (int nf = 0; nf < 4; nf++) {
            bh[nf] = *reinterpret_cast<const s8v*>(&sWh[(wn + nf * 16 + l16) * PIT + lk * 8]);
            bl[nf] = *reinterpret_cast<const s8v*>(&sWl[(wn + nf * 16 + l16) * PIT + lk * 8]);
        }
#pragma unroll
        for (int mf = 0; mf < 2; mf++)
#pragma unroll
            for (int nf = 0; nf < 4; nf++) {
                accv[mf][nf] = __builtin_amdgcn_mfma_f32_16x16x32_bf16(ah[mf], bh[nf], accv[mf][nf], 0, 0, 0);
                accv[mf][nf] = __builtin_amdgcn_mfma_f32_16x16x32_bf16(ah[mf], bl[nf], accv[mf][nf], 0, 0, 0);
                accv[mf][nf] = __builtin_amdgcn_mfma_f32_16x16x32_bf16(al[mf], bh[nf], accv[mf][nf], 0, 0, 0);
            }
        __syncthreads();
    }
    const float* rg = regime + (bm / T_) * R_;
#pragma unroll
    for (int mf = 0; mf < 2; mf++)
#pragma unroll
        for (int nf = 0; nf < 4; nf++) {
            int col = bn + wn + nf * 16 + l16;
            float rb = 0.f;
#pragma unroll
            for (int r = 0; r < R_; r++) rb += rg[r] * rw1t[r * D_ + col];
#pragma unroll
            for (int r = 0; r < 4; r++) {
                int rr = bm + wm + mf * 16 + lk * 4 + r;
                float v = accv[mf][nf][r] + bias[col] + rb;
                C[(size_t)rr * N + col] = siluf(v);
            }
        }
}

// ---------------- SSM scan v6: fused dt (bf16 feats x f32 weights), f32 x/z ----------------
__global__ __launch_bounds__(128) void scan_k(
    const float* __restrict__ xz, const ushort* __restrict__ xdblb,
    const float* __restrict__ bcint,
    const float* __restrict__ dt_w, const float* __restrict__ dt_b,
    const float* __restrict__ alr, const float* __restrict__ aim,
    const float* __restrict__ dvecp, ushort* __restrict__ ygb)
{
    int p = blockIdx.x;
    int blk = (p & 7) * 96 + (p >> 3);       // 768 = 8*96, bijective XCD clustering
    int b = blk / 192;
    int dbase = (blk % 192) * 4;
    int tid = threadIdx.x;                   // 0..127
    int ch = tid >> 5;                       // recurrence channel 0..3
    int s = tid & 31;
    int d = dbase + ch;
    __shared__ __align__(16) float sdx[64 * SPD];     // [t][{dt,x}x4ch]  2.5 KB
    __shared__ __align__(16) float sbc[64 * SPB];     // [t][{B,C}x32s]  16.5 KB
    __shared__ float sacc[SCH * 4][33];               // 33.8 KB
    int cch = tid & 3;
    float wdt[24];
#pragma unroll
    for (int k = 0; k < 24; k++) wdt[k] = dt_w[k * DI_ + dbase + cch];
    float dtbias = dt_b[dbase + cch];

    float negA = -__expf(alr[d * S_ + s]);
    float aimv = aim[d * S_ + s];
    float4 dv4 = *reinterpret_cast<const float4*>(dvecp + dbase);
    float dvc[4] = {dv4.x, dv4.y, dv4.z, dv4.w};
    float hre = 0.f, him = 0.f;
    const float* xzp = xz + (size_t)b * T_ * (2 * DI_);
    const ushort* xdp = xdblb + (size_t)b * T_ * 32;
    const float* bcp = bcint + (size_t)b * T_ * 64;
    ushort* ygp = ygb + (size_t)b * T_ * DI_;

    for (int c = 0; c < T_ / SCH; c++) {
        int tc = c * SCH;
        __syncthreads();
        // x staging (f32)
        if (tid < 64) {
            int t = tid;
            float4 x4 = *reinterpret_cast<const float4*>(xzp + (size_t)(tc + t) * (2 * DI_) + dbase);
            sdx[t * SPD + 1] = x4.x;
            sdx[t * SPD + 3] = x4.y;
            sdx[t * SPD + 5] = x4.z;
            sdx[t * SPD + 7] = x4.w;
        }
        // fused dt: 2 jobs/thread, each a K=24 dot (bf16 feats x f32 w) + softplus
        {
            int t0 = tid >> 2;
#pragma unroll
            for (int j = 0; j < 2; j++) {
                int t = t0 + j * 32;
                const ushort* xr = xdp + (size_t)(tc + t) * 32;
                u16x8 a0 = *reinterpret_cast<const u16x8*>(xr);
                u16x8 a1 = *reinterpret_cast<const u16x8*>(xr + 8);
                u16x8 a2 = *reinterpret_cast<const u16x8*>(xr + 16);
                float acc = dtbias;
#pragma unroll
                for (int k = 0; k < 8; k++) acc = fmaf(b2f((ushort)a0[k]), wdt[k], acc);
#pragma unroll
                for (int k = 0; k < 8; k++) acc = fmaf(b2f((ushort)a1[k]), wdt[8 + k], acc);
#pragma unroll
                for (int k = 0; k < 8; k++) acc = fmaf(b2f((ushort)a2[k]), wdt[16 + k], acc);
                float dtv = (acc > 0.f) ? acc + log1pf(__expf(-acc)) : log1pf(__expf(acc));
                sdx[t * SPD + 2 * cch] = dtv;
            }
        }
        // B/C staging (f32, pair-interleaved layout produced by xp epilogue)
#pragma unroll
        for (int i = 0; i < 8; i++) {
            int idx = tid + i * 128;
            int tt = idx >> 4, q = idx & 15;
            *reinterpret_cast<float4*>(&sbc[tt * SPB + 4 * q]) =
                *reinterpret_cast<const float4*>(bcp + (size_t)(tc + tt) * 64 + 4 * q);
        }
        __syncthreads();

        const float* dxr = &sdx[2 * ch];
        const float* bcr = &sbc[2 * s];
        float2 dx0 = *reinterpret_cast<const float2*>(dxr);
        float2 bc0 = *reinterpret_cast<const float2*>(bcr);
        float2 dx1 = *reinterpret_cast<const float2*>(dxr + SPD);
        float2 bc1 = *reinterpret_cast<const float2*>(bcr + SPB);
#pragma unroll 4
        for (int t = 0; t < SCH; t++) {
            float2 dx2 = make_float2(0.f, 0.f), bc2 = dx2;
            if (t + 2 < SCH) {
                dx2 = *reinterpret_cast<const float2*>(dxr + (t + 2) * SPD);
                bc2 = *reinterpret_cast<const float2*>(bcr + (t + 2) * SPB);
            }
            float e = __expf(negA * dx0.x);
            float sn, cs;
            __sincosf(aimv * dx0.x, &sn, &cs);
            float dre = e * cs, dim = e * sn;
            float u = dx0.x * dx0.y * bc0.x;
            float nre = fmaf(dre, hre, fmaf(-dim, him, u));
            him = fmaf(dre, him, dim * hre);
            hre = nre;
            sacc[t * 4 + ch][s] = hre * bc0.y;
            dx0 = dx1; bc0 = bc1; dx1 = dx2; bc1 = bc2;
        }
        __syncthreads();

#pragma unroll
        for (int p2 = 0; p2 < 2; p2++) {
            int r = tid + p2 * 128;
            int t = r >> 2, c4 = r & 3;
            float acc = 0.f;
#pragma unroll
            for (int s2 = 0; s2 < 32; s2++) acc += sacc[r][s2];
            float xv = sdx[t * SPD + 2 * c4 + 1];
            float zv = xzp[(size_t)(tc + t) * (2 * DI_) + DI_ + dbase + c4];
            float y = (acc + dvc[c4] * xv) * siluf(zv);
            ygp[(size_t)(tc + t) * DI_ + dbase + c4] = f2b(y);
        }
    }
}

// ---------------- gate logits ----------------
__global__ __launch_bounds__(256) void gl_k(const float* __restrict__ hmid,
                                            const float* __restrict__ rw2l,
                                            const float* __restrict__ rb2l, float* __restrict__ gl)
{
    int pid = blockIdx.x * 16 + (threadIdx.x >> 4);
    int li = threadIdx.x & 15;
    int t = pid / E_, e = pid - t * E_;
    const float* hp = hmid + (size_t)t * D_;
    float a = 0.f;
#pragma unroll 4
    for (int j = 0; j < D_ / 16; j++) {
        int k = li + j * 16;
        a += hp[k] * rw2l[k * E_ + e];
    }
#pragma unroll
    for (int o = 8; o > 0; o >>= 1) a += __shfl_xor(a, o, 16);
    if (li == 0) gl[t * E_ + e] = a + rb2l[e];
}

// ---------------- fused router + assign (wave-aggregated stats, guarded i1) ----------------
__global__ __launch_bounds__(1024) void router_assign_k(const float* __restrict__ gl,
                                                        float* __restrict__ tw,
                                                        int* __restrict__ glist,
                                                        int* __restrict__ tpos,
                                                        int* __restrict__ cnt,
                                                        float* __restrict__ statL)
{
    __shared__ float s_p[E_], s_c[E_];
    __shared__ int scnt[E_];
    int tid = threadIdx.x;
    if (tid < E_) { s_p[tid] = 0.f; s_c[tid] = 0.f; scnt[tid] = 0; }
    __syncthreads();
    float lp[E_] = {0.f, 0.f, 0.f, 0.f, 0.f, 0.f};
    float lc[E_] = {0.f, 0.f, 0.f, 0.f, 0.f, 0.f};
    for (int t = tid; t < BT_; t += 1024) {
        float g[E_];
        for (int e = 0; e < E_; e++) g[e] = gl[t * E_ + e];
        int i0 = 0; float v0 = g[0];
        for (int e = 1; e < E_; e++) if (g[e] > v0) { v0 = g[e]; i0 = e; }
        int i1 = -1; float v1 = -1e30f;
        for (int e = 0; e < E_; e++) if (e != i0 && g[e] > v1) { v1 = g[e]; i1 = e; }
        if (i1 < 0) i1 = (i0 == 0) ? 1 : 0;
        float e1 = __expf(v1 - v0);
        float inv = 1.f / (1.f + e1);
        tw[t * 2] = inv; tw[t * 2 + 1] = e1 * inv;
        int pos0 = atomicAdd(&scnt[i0], 1);
        glist[i0 * BT_ + pos0] = t;
        tpos[2 * t] = i0 * BT_ + pos0;
        int pos1 = atomicAdd(&scnt[i1], 1);
        glist[i1 * BT_ + pos1] = t;
        tpos[2 * t + 1] = i1 * BT_ + pos1;
        float pb[E_], se = 0.f;
        for (int e = 0; e < E_; e++) { pb[e] = __expf(g[e] - v0); se += pb[e]; }
        float rse = 1.f / se;
#pragma unroll
        for (int e = 0; e < E_; e++) {
            lp[e] += pb[e] * rse;
            lc[e] += (i0 == e) ? 1.f : 0.f;
        }
    }
#pragma unroll
    for (int e = 0; e < E_; e++) {
        float v = lp[e], u = lc[e];
#pragma unroll
        for (int o = 32; o > 0; o >>= 1) { v += __shfl_xor(v, o); u += __shfl_xor(u, o); }
        if ((tid & 63) == 0) { atomicAdd(&s_p[e], v); atomicAdd(&s_c[e], u); }
    }
    __syncthreads();
    if (tid < E_) {
        cnt[tid] = scnt[tid];
        statL[tid] = s_p[tid];
        statL[8 + tid] = s_c[tid];
    }
}

__global__ void write_aux_k(const float* __restrict__ stats, float* __restrict__ out)
{
    if (threadIdx.x == 0 && blockIdx.x == 0) {
        float aux = 0.f;
        for (int l = 0; l < L_; l++) {
            float s = 0.f;
            for (int e = 0; e < E_; e++) s += stats[l * 16 + e] * stats[l * 16 + 8 + e];
            aux += 0.01f * (float)E_ * s / ((float)BT_ * (float)BT_);
        }
        out[BT_ * D_] = aux;
    }
}

// ---------------- launch ----------------
extern "C" void kernel_launch(void* const* d_in, const int* in_sizes, int n_in,
                              void* d_out, int out_size, void* d_ws, size_t ws_size,
                              hipStream_t stream)
{
    const float* x       = (const float*)d_in[0];
    const float* regime  = (const float*)d_in[1];
    const float* film_w1 = (const float*)d_in[2];
    const float* film_b1 = (const float*)d_in[3];
    const float* film_w2 = (const float*)d_in[4];
    const float* film_b2 = (const float*)d_in[5];
    const float* ssm_ng  = (const float*)d_in[6];
    const float* ssm_nb  = (const float*)d_in[7];
    const float* in_w    = (const float*)d_in[8];
    const float* xp_w    = (const float*)d_in[9];
    const float* dt_w    = (const float*)d_in[10];
    const float* dt_b    = (const float*)d_in[11];
    const float* alr     = (const float*)d_in[12];
    const float* aimp    = (const float*)d_in[13];
    const float* ssm_d   = (const float*)d_in[14];
    const float* out_w   = (const float*)d_in[15];
    const float* moe_ng  = (const float*)d_in[16];
    const float* moe_nb  = (const float*)d_in[17];
    const float* r_w1    = (const float*)d_in[18];
    const float* r_b1    = (const float*)d_in[19];
    const float* r_w2    = (const float*)d_in[20];
    const float* r_b2    = (const float*)d_in[21];
    const float* e_w1    = (const float*)d_in[22];
    const float* e_b1    = (const float*)d_in[23];
    const float* e_w2    = (const float*)d_in[24];
    const float* e_b2    = (const float*)d_in[25];
    const float* fin_g   = (const float*)d_in[26];
    const float* fin_b   = (const float*)d_in[27];

    float* ws = (float*)d_ws;
    size_t o = 0;
    float*  h      = ws + o; o += 786432;
    float*  stats  = ws + o; o += 64;
    ushort* xnH    = (ushort*)(ws + o); o += 393216;
    ushort* xnL    = (ushort*)(ws + o); o += 393216;
    float*  gl     = ws + o; o += 12288;
    float*  tw     = ws + o; o += 4096;
    int*    glist  = (int*)(ws + o); o += 12288;
    int*    tpos   = (int*)(ws + o); o += 4096;
    int*    cnt    = (int*)(ws + o); o += 16;
    ushort* in_wb  = (ushort*)(ws + o); o += 589824;
    ushort* xp_wb  = (ushort*)(ws + o); o += 67584;
    ushort* dt_wb  = (ushort*)(ws + o); o += 18432;   // written by conv_k, unused (dt fused)
    ushort* out_wb = (ushort*)(ws + o); o += 294912;
    ushort* e1b    = (ushort*)(ws + o); o += 1179648;
    ushort* e2b    = (ushort*)(ws + o); o += 1179648;
    ushort* r1h    = (ushort*)(ws + o); o += 147456;
    ushort* r1l    = (ushort*)(ws + o); o += 147456;
    // phase-aliased pool (SSM scratch / MoE scratch)
    float*  xz    = ws + o;                            // [2048][1536] f32 = 3145728 f
    ushort* xzb   = (ushort*)(ws + o + 3145728);       // [2048][768] bf16 = 786432 f
    ushort* xdblb = (ushort*)(ws + o + 3932160);       // [2048][32] bf16 = 32768 f
    float*  bcint = ws + o + 3964928;                  // [2048][64] f32 = 131072 f
    ushort* ygb   = (ushort*)(ws + o + 4096000);       // [2048][768] bf16 = 786432 f -> 4882432
    float*  hmid  = ws + o;                            // MoE phase (aliases xz, dead)
    ushort* eohb  = (ushort*)(ws + o + 786432);        // [6][2048][512] bf16
    ushort* eodb  = (ushort*)(ws + o + 3932160);       // [6][2048][384] bf16 -> 5111808
    float*  gb    = ws + o;                            // film temp (pool, pre-loop)

    conv_k<<<2048, 256, 0, stream>>>(in_w, xp_w, dt_w, out_w, e_w1, e_w2, r_w1,
                                     in_wb, xp_wb, dt_wb, out_wb, e1b, e2b, r1h, r1l);
    film_k<<<B_, 2 * D_, 0, stream>>>(regime, film_w1, film_b1, film_w2, film_b2, gb, stats);
    film_apply_k<<<(B_ * T_ * D_ + 255) / 256, 256, 0, stream>>>(x, gb, h);

    for (int l = 0; l < L_; l++) {
        // ---- SSM block ----
        if (l == 0)
            ln_k<1><<<BT_, 256, 0, stream>>>(h, ssm_ng, ssm_nb, nullptr, xnH, nullptr);
        // (for l>0, xnH was produced by selln_k<1> at the end of the previous MoE block)
        gemm_b<2, false, false, false><<<dim3(24, 32), 256, 0, stream>>>(
            xnH, D_, 0, in_wb + (size_t)l * 589824, 2 * DI_, 0,
            xz, 2 * DI_, 0, xzb, DI_, 0, DI_,
            nullptr, 0, nullptr, nullptr, 2 * DI_, D_, 0, 0);
        gemm_b<3, true, false, false><<<dim3(2, 32), 256, 0, stream>>>(
            xzb, DI_, 0, xp_wb + (size_t)l * 67584, XPN_, 0,
            bcint, 64, 0, xdblb, 32, 0, 32,
            nullptr, 0, nullptr, nullptr, XPN_, DI_, 0, 0);
        scan_k<<<B_ * 192, 128, 0, stream>>>(
            xz, xdblb, bcint,
            dt_w + (size_t)l * DTR_ * DI_, dt_b + l * DI_,
            alr + (size_t)l * DI_ * S_, aimp + (size_t)l * DI_ * S_,
            ssm_d + l * DI_, ygb);
        gemm_b<0, false, false, false><<<dim3(6, 32), 256, 0, stream>>>(
            ygb, DI_, 0, out_wb + (size_t)l * 294912, D_, 0,
            h, D_, 0, nullptr, 0, 0, 0,
            nullptr, 0, nullptr, nullptr, D_, DI_, 0, 1);

        // ---- MoE block ----
        ln_k<2><<<BT_, 256, 0, stream>>>(h, moe_ng + l * D_, moe_nb + l * D_, nullptr, xnH, xnL);
        gemm3_k<<<dim3(3, 32), 256, 0, stream>>>(
            xnH, xnL, D_, r1h + (size_t)l * 147456, r1l + (size_t)l * 147456, D_,
            hmid, r_b1 + l * D_,
            regime, r_w1 + (size_t)l * ((D_ + R_) * D_) + (size_t)D_ * D_,
            D_, D_);
        gl_k<<<BT_ * E_ / 16, 256, 0, stream>>>(hmid, r_w2 + (size_t)l * D_ * E_, r_b2 + l * E_, gl);
        router_assign_k<<<1, 1024, 0, stream>>>(gl, tw, glist, tpos, cnt, stats + l * 16);
        gemm_b<1, false, false, true><<<dim3(8, 32, 6), 256, 0, stream>>>(
            xnH, D_, 0, e1b + (size_t)l * 1179648, H_, (long)D_ * H_,
            nullptr, 0, 0, eohb, H_, (long)BT_ * H_, H_,
            e_b1 + (size_t)l * E_ * H_, H_, glist, cnt, H_, D_, 1, 0);
        gemm_b<1, false, false, false><<<dim3(6, 32, 6), 256, 0, stream>>>(
            eohb, H_, (long)BT_ * H_, e2b + (size_t)l * 1179648, D_, (long)H_ * D_,
            nullptr, 0, 0, eodb, D_, (long)BT_ * D_, D_,
            e_b2 + (size_t)l * E_ * D_, D_, nullptr, cnt, D_, H_, 0, 0);
        if (l < L_ - 1)
            selln_k<1><<<BT_, 256, 0, stream>>>(h, eodb, tw, tpos,
                ssm_ng + (l + 1) * D_, ssm_nb + (l + 1) * D_, nullptr, xnH, nullptr);
        else
            selln_k<0><<<BT_, 256, 0, stream>>>(h, eodb, tw, tpos,
                fin_g, fin_b, (float*)d_out, nullptr, nullptr);
    }

    write_aux_k<<<1, 64, 0, stream>>>(stats, (float*)d_out);
}

// Round 14
// 478.193 us; speedup vs baseline: 1.2810x; 1.0238x over previous
//
#include <hip/hip_runtime.h>
#include <hip/hip_bf16.h>
#include <math.h>

#define B_   4
#define T_   512
#define D_   384
#define S_   32
#define E_   6
#define H_   512
#define R_   5
#define L_   2
#define DI_  768
#define DTR_ 24
#define BT_  2048
#define XPN_ 88   // DTR + 2*S
#define SCH  64   // scan time-chunk
#define PIT  40   // GEMM LDS row pitch in ushorts (80 B)
#define SPD  12   // scan sdx pitch: [t][{dt,x}x4ch | z x4ch]
#define SPB  66   // scan sbc pitch: [t][{B,C}x32s]

typedef short s8v __attribute__((ext_vector_type(8)));
typedef float f32x4 __attribute__((ext_vector_type(4)));
typedef ushort u16x8 __attribute__((ext_vector_type(8)));

__device__ __forceinline__ float siluf(float x) { return x / (1.f + __expf(-x)); }
__device__ __forceinline__ ushort f2b(float f) {
    unsigned u = __float_as_uint(f);
    return (ushort)((u + 0x7FFFu + ((u >> 16) & 1u)) >> 16);
}
__device__ __forceinline__ float b2f(ushort h) { return __uint_as_float(((unsigned)h) << 16); }

// ---------------- weight pre-conversion ----------------
#define CN0 1179648L  // in_w
#define CN1 135168L   // xp_w
#define CN2 36864L    // dt_w (unused after dt-fusion)
#define CN3 589824L   // out_w
#define CN4 2359296L  // e_w1
#define CN5 2359296L  // e_w2
#define CN6 294912L   // r_w1[:384,:] hi/lo (2 layers)
__global__ void conv_k(const float* __restrict__ in_w, const float* __restrict__ xp_w,
                       const float* __restrict__ dt_w, const float* __restrict__ out_w,
                       const float* __restrict__ e_w1, const float* __restrict__ e_w2,
                       const float* __restrict__ r_w1,
                       ushort* __restrict__ in_wb, ushort* __restrict__ xp_wb,
                       ushort* __restrict__ dt_wb, ushort* __restrict__ out_wb,
                       ushort* __restrict__ e1b, ushort* __restrict__ e2b,
                       ushort* __restrict__ r1h, ushort* __restrict__ r1l)
{
    const long total = CN0 + CN1 + CN2 + CN3 + CN4 + CN5 + CN6;
    long stride = (long)gridDim.x * 256;
    for (long i = (long)blockIdx.x * 256 + threadIdx.x; i < total; i += stride) {
        long j = i;
        if (j < CN0) { in_wb[j] = f2b(in_w[j]); continue; }
        j -= CN0;
        if (j < CN1) { xp_wb[j] = f2b(xp_w[j]); continue; }
        j -= CN1;
        if (j < CN2) { dt_wb[j] = f2b(dt_w[j]); continue; }
        j -= CN2;
        if (j < CN3) { out_wb[j] = f2b(out_w[j]); continue; }
        j -= CN3;
        if (j < CN4) { e1b[j] = f2b(e_w1[j]); continue; }
        j -= CN4;
        if (j < CN5) { e2b[j] = f2b(e_w2[j]); continue; }
        j -= CN5;
        {
            long l = j / 147456, rem = j - l * 147456;
            float v = r_w1[l * (long)((D_ + R_) * D_) + rem];
            ushort hv = f2b(v);
            r1h[j] = hv;
            r1l[j] = f2b(v - b2f(hv));
        }
    }
}

// ---------------- FiLM ----------------
__global__ void film_k(const float* __restrict__ regime, const float* __restrict__ w1,
                       const float* __restrict__ b1, const float* __restrict__ w2,
                       const float* __restrict__ b2, float* __restrict__ gb,
                       float* __restrict__ stats)
{
    int b = blockIdx.x;
    int tid = threadIdx.x;
    if (b == 0 && tid < 40) stats[tid] = 0.f;
    __shared__ float t1[D_];
    if (tid < D_) {
        float a = b1[tid];
        for (int r = 0; r < R_; r++) a += regime[b * R_ + r] * w1[r * D_ + tid];
        t1[tid] = siluf(a);
    }
    __syncthreads();
    float a = b2[tid];
    for (int d = 0; d < D_; d++) a += t1[d] * w2[d * (2 * D_) + tid];
    gb[b * (2 * D_) + tid] = a;
}

__global__ void film_apply_k(const float* __restrict__ x, const float* __restrict__ gb,
                             float* __restrict__ h)
{
    int i = blockIdx.x * 256 + threadIdx.x;
    if (i >= B_ * T_ * D_) return;
    int b = i / (T_ * D_);
    int d = i % D_;
    h[i] = x[i] * (1.f + gb[b * (2 * D_) + d]) + gb[b * (2 * D_) + D_ + d];
}

// ---------------- LayerNorm: MODE 0 = f32 out, 1 = bf16 out, 2 = bf16 hi+lo ----------------
template<int MODE>
__global__ __launch_bounds__(256) void ln_k(const float* __restrict__ in,
                                            const float* __restrict__ g, const float* __restrict__ b,
                                            float* __restrict__ outF,
                                            ushort* __restrict__ outH, ushort* __restrict__ outL)
{
    int row = blockIdx.x;
    int tid = threadIdx.x;
    const float* x = in + (size_t)row * D_;
    float v0 = x[tid];
    float v1 = (tid < D_ - 256) ? x[256 + tid] : 0.f;
    float s = v0 + v1, ss = v0 * v0 + v1 * v1;
#pragma unroll
    for (int o = 32; o > 0; o >>= 1) { s += __shfl_xor(s, o); ss += __shfl_xor(ss, o); }
    __shared__ float sb[8];
    int w = tid >> 6;
    if ((tid & 63) == 0) { sb[w] = s; sb[4 + w] = ss; }
    __syncthreads();
    s = sb[0] + sb[1] + sb[2] + sb[3];
    ss = sb[4] + sb[5] + sb[6] + sb[7];
    float mean = s * (1.f / D_);
    float var = ss * (1.f / D_) - mean * mean;
    float rstd = rsqrtf(var + 1e-5f);
#pragma unroll
    for (int p = 0; p < 2; p++) {
        int c = tid + p * 256;
        if (c >= D_) break;
        float v = (p ? v1 : v0);
        float o = (v - mean) * rstd * g[c] + b[c];
        size_t idx = (size_t)row * D_ + c;
        if (MODE == 0) outF[idx] = o;
        else {
            ushort hv = f2b(o);
            outH[idx] = hv;
            if (MODE == 2) outL[idx] = f2b(o - b2f(hv));
        }
    }
}

// ---------------- fused sel + LayerNorm ----------------
template<int MODE>
__global__ __launch_bounds__(256) void selln_k(float* __restrict__ h,
                                               const ushort* __restrict__ eodb,
                                               const float* __restrict__ tw,
                                               const int* __restrict__ tpos,
                                               const float* __restrict__ g, const float* __restrict__ b,
                                               float* __restrict__ outF,
                                               ushort* __restrict__ outH, ushort* __restrict__ outL)
{
    int row = blockIdx.x;
    int tid = threadIdx.x;
    float* hp = h + (size_t)row * D_;
    int p0 = tpos[row * 2], p1 = tpos[row * 2 + 1];
    float w0 = tw[row * 2], w1 = tw[row * 2 + 1];
    const ushort* e0 = eodb + (size_t)p0 * D_;
    const ushort* e1 = eodb + (size_t)p1 * D_;
    float v0 = hp[tid] + w0 * b2f(e0[tid]) + w1 * b2f(e1[tid]);
    float v1 = 0.f;
    if (tid < D_ - 256) v1 = hp[256 + tid] + w0 * b2f(e0[256 + tid]) + w1 * b2f(e1[256 + tid]);
    hp[tid] = v0;
    if (tid < D_ - 256) hp[256 + tid] = v1;
    float s = v0 + v1, ss = v0 * v0 + v1 * v1;
#pragma unroll
    for (int o = 32; o > 0; o >>= 1) { s += __shfl_xor(s, o); ss += __shfl_xor(ss, o); }
    __shared__ float sb[8];
    int w = tid >> 6;
    if ((tid & 63) == 0) { sb[w] = s; sb[4 + w] = ss; }
    __syncthreads();
    s = sb[0] + sb[1] + sb[2] + sb[3];
    ss = sb[4] + sb[5] + sb[6] + sb[7];
    float mean = s * (1.f / D_);
    float var = ss * (1.f / D_) - mean * mean;
    float rstd = rsqrtf(var + 1e-5f);
#pragma unroll
    for (int p = 0; p < 2; p++) {
        int c = tid + p * 256;
        if (c >= D_) break;
        float v = (p ? v1 : v0);
        float o = (v - mean) * rstd * g[c] + b[c];
        size_t idx = (size_t)row * D_ + c;
        if (MODE == 0) outF[idx] = o;
        else {
            ushort hv = f2b(o);
            outH[idx] = hv;
            if (MODE == 2) outL[idx] = f2b(o - b2f(hv));
        }
    }
}

// ---------------- bf16 MFMA GEMM, 64x64 tile, double-buffered LDS ----------------
// OM: 0 = f32 out, 1 = bf16 out, 2 = both, 3 = xp-special (bf16 col<nb16 + bcint scatter col>=24)
template<int OM, bool NG, bool KG, bool GATHER>
__global__ __launch_bounds__(256) void gemm_b(
    const ushort* __restrict__ A, int lda, long aOff,
    const ushort* __restrict__ W, int ldw, long wOff,
    float* __restrict__ C, int ldc, long cOff,
    ushort* __restrict__ Cb, int ldcb, long cbOff, int nb16,
    const float* __restrict__ bias, long bOff,
    const int* __restrict__ glist, const int* __restrict__ gcnt,
    int N, int K, int act, int acc)
{
    __shared__ __align__(16) ushort As[2][64 * PIT];
    __shared__ __align__(16) ushort Bs[2][64 * PIT];
    const int z = blockIdx.z;
    const int bm = blockIdx.y * 64, bn = blockIdx.x * 64;
    int cnt = 0;
    if (gcnt) { cnt = gcnt[z]; if (bm >= cnt) return; }
    const int tid = threadIdx.x, w = tid >> 6, lane = tid & 63;
    const int wm = (w >> 1) * 32, wn = (w & 1) * 32;
    const int l16 = lane & 15, lk = lane >> 4;
    const int r0 = tid >> 2, c0 = (tid & 3) * 8;
    const ushort* Ab;
    if (GATHER) {
        int gr = bm + r0;
        int t_idx = (gr < cnt) ? glist[(size_t)z * BT_ + gr] : 0;
        Ab = A + (size_t)t_idx * lda;
    } else {
        Ab = A + (size_t)z * aOff + (size_t)(bm + r0) * lda;
    }
    const ushort* Wb = W + (size_t)z * wOff;

    f32x4 accv[2][2];
#pragma unroll
    for (int i = 0; i < 2; i++)
#pragma unroll
        for (int j = 0; j < 2; j++) accv[i][j] = (f32x4)0.f;

    u16x8 arg;
    ushort wrg[8];
    auto LOADA = [&](int k0) {
        arg = *reinterpret_cast<const u16x8*>(Ab + k0 + c0);
    };
    auto LOADW = [&](int k0) {
#pragma unroll
        for (int i = 0; i < 8; i++) {
            int kk = k0 + w * 8 + i;
            bool ok = (!KG || kk < K) && (!NG || (bn + lane) < N);
            wrg[i] = ok ? Wb[(size_t)kk * ldw + bn + lane] : (ushort)0;
        }
    };
    auto STORE = [&](int buf) {
        *reinterpret_cast<u16x8*>(&As[buf][r0 * PIT + c0]) = arg;
        *reinterpret_cast<ushort4*>(&Bs[buf][lane * PIT + w * 8]) =
            make_ushort4(wrg[0], wrg[1], wrg[2], wrg[3]);
        *reinterpret_cast<ushort4*>(&Bs[buf][lane * PIT + w * 8 + 4]) =
            make_ushort4(wrg[4], wrg[5], wrg[6], wrg[7]);
    };

    LOADA(0); LOADW(0); STORE(0);
    __syncthreads();
    const int NIT = (K + 31) / 32;
    for (int it = 0; it < NIT; it++) {
        int cur = it & 1;
        bool more = (it + 1 < NIT);
        if (more) { LOADA((it + 1) * 32); LOADW((it + 1) * 32); }
        s8v af[2], bfr[2];
#pragma unroll
        for (int mf = 0; mf < 2; mf++)
            af[mf] = *reinterpret_cast<const s8v*>(&As[cur][(wm + mf * 16 + l16) * PIT + lk * 8]);
#pragma unroll
        for (int nf = 0; nf < 2; nf++)
            bfr[nf] = *reinterpret_cast<const s8v*>(&Bs[cur][(wn + nf * 16 + l16) * PIT + lk * 8]);
#pragma unroll
        for (int mf = 0; mf < 2; mf++)
#pragma unroll
            for (int nf = 0; nf < 2; nf++)
                accv[mf][nf] = __builtin_amdgcn_mfma_f32_16x16x32_bf16(af[mf], bfr[nf], accv[mf][nf], 0, 0, 0);
        if (more) { STORE(cur ^ 1); __syncthreads(); }
    }

    const float* biasb = bias ? bias + (size_t)z * bOff : nullptr;
#pragma unroll
    for (int mf = 0; mf < 2; mf++) {
#pragma unroll
        for (int nf = 0; nf < 2; nf++) {
            int col = bn + wn + nf * 16 + l16;
            if (NG && col >= N) continue;
#pragma unroll
            for (int r = 0; r < 4; r++) {
                int rr = bm + wm + mf * 16 + lk * 4 + r;
                if (gcnt && rr >= cnt) continue;
                float v = accv[mf][nf][r];
                if (biasb) v += biasb[col];
                if (act == 1) v = siluf(v);
                else if (act == 2) v = (v > 0.f) ? v + log1pf(__expf(-v)) : log1pf(__expf(v));
                if (OM == 0 || OM == 2) {
                    float* Cz = C + (size_t)z * cOff;
                    size_t ci = (size_t)rr * ldc + col;
                    Cz[ci] = acc ? (Cz[ci] + v) : v;
                }
                if (OM == 1 || OM == 2) {
                    if (col < nb16)
                        (Cb + (size_t)z * cbOff)[(size_t)rr * ldcb + col] = f2b(v);
                }
                if (OM == 3) {
                    if (col < nb16)
                        Cb[(size_t)rr * ldcb + col] = f2b(v);
                    if (col >= 24) {        // bcint scatter: {B[s],C[s]} interleaved
                        int q = col - 24;
                        C[(size_t)rr * 64 + ((q < 32) ? (2 * q) : (2 * (q - 32) + 1))] = v;
                    }
                }
            }
        }
    }
}

// ---------------- bf16x3 router GEMM + fused gate-logit partials ----------------
// BM=64 x BN=64, 4 waves 2x2. Epilogue: silu'd tile -> LDS, then per-block partial
// gl over its 64 cols written to glp[blockIdx.x][row][e]. No hmid materialization.
__global__ __launch_bounds__(256) void gemm3_k(
    const ushort* __restrict__ Ah, const ushort* __restrict__ Al, int lda,
    const ushort* __restrict__ Wh, const ushort* __restrict__ Wl, int ldw,
    const float* __restrict__ bias,
    const float* __restrict__ regime, const float* __restrict__ rw1t,
    const float* __restrict__ rw2l,
    float* __restrict__ glp,
    int K)
{
    __shared__ __align__(16) ushort sAh[64 * PIT], sAl[64 * PIT];
    __shared__ __align__(16) ushort sWh[64 * PIT], sWl[64 * PIT];
    __shared__ __align__(16) float sV[64 * 66];
    const int bm = blockIdx.y * 64, bn = blockIdx.x * 64;
    const int tid = threadIdx.x, w = tid >> 6, lane = tid & 63;
    const int wm = (w >> 1) * 32, wn = (w & 1) * 32;
    const int l16 = lane & 15, lk = lane >> 4;
    const int r0 = tid >> 2, c0 = (tid & 3) * 8;
    f32x4 accv[2][2];
#pragma unroll
    for (int i = 0; i < 2; i++)
#pragma unroll
        for (int j = 0; j < 2; j++) accv[i][j] = (f32x4)0.f;

    for (int k0 = 0; k0 < K; k0 += 32) {
        *reinterpret_cast<u16x8*>(&sAh[r0 * PIT + c0]) =
            *reinterpret_cast<const u16x8*>(Ah + (size_t)(bm + r0) * lda + k0 + c0);
        *reinterpret_cast<u16x8*>(&sAl[r0 * PIT + c0]) =
            *reinterpret_cast<const u16x8*>(Al + (size_t)(bm + r0) * lda + k0 + c0);
        {
            ushort th[8], tl[8];
#pragma unroll
            for (int i = 0; i < 8; i++) {
                int kk = k0 + w * 8 + i;
                th[i] = Wh[(size_t)kk * ldw + bn + lane];
                tl[i] = Wl[(size_t)kk * ldw + bn + lane];
            }
            *reinterpret_cast<ushort4*>(&sWh[lane * PIT + w * 8])     = make_ushort4(th[0], th[1], th[2], th[3]);
            *reinterpret_cast<ushort4*>(&sWh[lane * PIT + w * 8 + 4]) = make_ushort4(th[4], th[5], th[6], th[7]);
            *reinterpret_cast<ushort4*>(&sWl[lane * PIT + w * 8])     = make_ushort4(tl[0], tl[1], tl[2], tl[3]);
            *reinterpret_cast<ushort4*>(&sWl[lane * PIT + w * 8 + 4]) = make_ushort4(tl[4], tl[5], tl[6], tl[7]);
        }
        __syncthreads();
        s8v ah[2], al[2], bh[2], bl[2];
#pragma unroll
        for (int mf = 0; mf < 2; mf++) {
            ah[mf] = *reinterpret_cast<const s8v*>(&sAh[(wm + mf * 16 + l16) * PIT + lk * 8]);
            al[mf] = *reinterpret_cast<const s8v*>(&sAl[(wm + mf * 16 + l16) * PIT + lk * 8]);
        }
#pragma unroll
        for (int nf = 0; nf < 2; nf++) {
            bh[nf] = *reinterpret_cast<const s8v*>(&sWh[(wn + nf * 16 + l16) * PIT + lk * 8]);
            bl[nf] = *reinterpret_cast<const s8v*>(&sWl[(wn + nf * 16 + l16) * PIT + lk * 8]);
        }
#pragma unroll
        for (int mf = 0; mf < 2; mf++)
#pragma unroll
            for (int nf = 0; nf < 2; nf++) {
                accv[mf][nf] = __builtin_amdgcn_mfma_f32_16x16x32_bf16(ah[mf], bh[nf], accv[mf][nf], 0, 0, 0);
                accv[mf][nf] = __builtin_amdgcn_mfma_f32_16x16x32_bf16(ah[mf], bl[nf], accv[mf][nf], 0, 0, 0);
                accv[mf][nf] = __builtin_amdgcn_mfma_f32_16x16x32_bf16(al[mf], bh[nf], accv[mf][nf], 0, 0, 0);
            }
        __syncthreads();
    }
    // epilogue: silu(acc + bias + regc) -> sV
    const float* rg = regime + (bm / T_) * R_;
#pragma unroll
    for (int nf = 0; nf < 2; nf++) {
        int col = bn + wn + nf * 16 + l16;
        float rb = bias[col - bn + bn];   // bias[col]
#pragma unroll
        for (int r = 0; r < R_; r++) rb += rg[r] * rw1t[r * D_ + col];
#pragma unroll
        for (int mf = 0; mf < 2; mf++)
#pragma unroll
            for (int r = 0; r < 4; r++) {
                int rr = wm + mf * 16 + lk * 4 + r;
                sV[rr * 66 + (col - bn)] = siluf(accv[mf][nf][r] + rb);
            }
    }
    __syncthreads();
    // per-block gl partial: 64 rows x 6 experts, dot over this block's 64 cols
    for (int job = tid; job < 64 * E_; job += 256) {
        int row = job / E_, e = job - row * E_;
        float a = 0.f;
#pragma unroll 8
        for (int c = 0; c < 64; c++)
            a += sV[row * 66 + c] * rw2l[(size_t)(bn + c) * E_ + e];
        glp[(size_t)blockIdx.x * (BT_ * E_) + (size_t)(bm + row) * E_ + e] = a;
    }
}

// ---------------- SSM scan v7: fused dt, z staged in LDS (SPD=12) ----------------
__global__ __launch_bounds__(128) void scan_k(
    const float* __restrict__ xz, const ushort* __restrict__ xdblb,
    const float* __restrict__ bcint,
    const float* __restrict__ dt_w, const float* __restrict__ dt_b,
    const float* __restrict__ alr, const float* __restrict__ aim,
    const float* __restrict__ dvecp, ushort* __restrict__ ygb)
{
    int p = blockIdx.x;
    int blk = (p & 7) * 96 + (p >> 3);       // 768 = 8*96, bijective XCD clustering
    int b = blk / 192;
    int dbase = (blk % 192) * 4;
    int tid = threadIdx.x;                   // 0..127
    int ch = tid >> 5;
    int s = tid & 31;
    int d = dbase + ch;
    __shared__ __align__(16) float sdx[64 * SPD];     // 3.0 KB: [t][dt,x x4 | z x4]
    __shared__ __align__(16) float sbc[64 * SPB];     // 16.5 KB
    __shared__ float sacc[SCH * 4][33];               // 33.8 KB  (total 53760 B, 3 blk/CU)
    int cch = tid & 3;
    float wdt[24];
#pragma unroll
    for (int k = 0; k < 24; k++) wdt[k] = dt_w[k * DI_ + dbase + cch];
    float dtbias = dt_b[dbase + cch];

    float negA = -__expf(alr[d * S_ + s]);
    float aimv = aim[d * S_ + s];
    float4 dv4 = *reinterpret_cast<const float4*>(dvecp + dbase);
    float dvc[4] = {dv4.x, dv4.y, dv4.z, dv4.w};
    float hre = 0.f, him = 0.f;
    const float* xzp = xz + (size_t)b * T_ * (2 * DI_);
    const ushort* xdp = xdblb + (size_t)b * T_ * 32;
    const float* bcp = bcint + (size_t)b * T_ * 64;
    ushort* ygp = ygb + (size_t)b * T_ * DI_;

    for (int c = 0; c < T_ / SCH; c++) {
        int tc = c * SCH;
        __syncthreads();
        if (tid < 64) {
            int t = tid;
            float4 x4 = *reinterpret_cast<const float4*>(xzp + (size_t)(tc + t) * (2 * DI_) + dbase);
            float4 z4 = *reinterpret_cast<const float4*>(xzp + (size_t)(tc + t) * (2 * DI_) + DI_ + dbase);
            sdx[t * SPD + 1] = x4.x;
            sdx[t * SPD + 3] = x4.y;
            sdx[t * SPD + 5] = x4.z;
            sdx[t * SPD + 7] = x4.w;
            sdx[t * SPD + 8]  = z4.x;
            sdx[t * SPD + 9]  = z4.y;
            sdx[t * SPD + 10] = z4.z;
            sdx[t * SPD + 11] = z4.w;
        }
        {
            int t0 = tid >> 2;
#pragma unroll
            for (int j = 0; j < 2; j++) {
                int t = t0 + j * 32;
                const ushort* xr = xdp + (size_t)(tc + t) * 32;
                u16x8 a0 = *reinterpret_cast<const u16x8*>(xr);
                u16x8 a1 = *reinterpret_cast<const u16x8*>(xr + 8);
                u16x8 a2 = *reinterpret_cast<const u16x8*>(xr + 16);
                float acc = dtbias;
#pragma unroll
                for (int k = 0; k < 8; k++) acc = fmaf(b2f((ushort)a0[k]), wdt[k], acc);
#pragma unroll
                for (int k = 0; k < 8; k++) acc = fmaf(b2f((ushort)a1[k]), wdt[8 + k], acc);
#pragma unroll
                for (int k = 0; k < 8; k++) acc = fmaf(b2f((ushort)a2[k]), wdt[16 + k], acc);
                float dtv = (acc > 0.f) ? acc + log1pf(__expf(-acc)) : log1pf(__expf(acc));
                sdx[t * SPD + 2 * cch] = dtv;
            }
        }
#pragma unroll
        for (int i = 0; i < 8; i++) {
            int idx = tid + i * 128;
            int tt = idx >> 4, q = idx & 15;
            *reinterpret_cast<float4*>(&sbc[tt * SPB + 4 * q]) =
                *reinterpret_cast<const float4*>(bcp + (size_t)(tc + tt) * 64 + 4 * q);
        }
        __syncthreads();

        const float* dxr = &sdx[2 * ch];
        const float* bcr = &sbc[2 * s];
        float2 dx0 = *reinterpret_cast<const float2*>(dxr);
        float2 bc0 = *reinterpret_cast<const float2*>(bcr);
        float2 dx1 = *reinterpret_cast<const float2*>(dxr + SPD);
        float2 bc1 = *reinterpret_cast<const float2*>(bcr + SPB);
#pragma unroll 4
        for (int t = 0; t < SCH; t++) {
            float2 dx2 = make_float2(0.f, 0.f), bc2 = dx2;
            if (t + 2 < SCH) {
                dx2 = *reinterpret_cast<const float2*>(dxr + (t + 2) * SPD);
                bc2 = *reinterpret_cast<const float2*>(bcr + (t + 2) * SPB);
            }
            float e = __expf(negA * dx0.x);
            float sn, cs;
            __sincosf(aimv * dx0.x, &sn, &cs);
            float dre = e * cs, dim = e * sn;
            float u = dx0.x * dx0.y * bc0.x;
            float nre = fmaf(dre, hre, fmaf(-dim, him, u));
            him = fmaf(dre, him, dim * hre);
            hre = nre;
            sacc[t * 4 + ch][s] = hre * bc0.y;
            dx0 = dx1; bc0 = bc1; dx1 = dx2; bc1 = bc2;
        }
        __syncthreads();

#pragma unroll
        for (int p2 = 0; p2 < 2; p2++) {
            int r = tid + p2 * 128;
            int t = r >> 2, c4 = r & 3;
            float acc = 0.f;
#pragma unroll
            for (int s2 = 0; s2 < 32; s2++) acc += sacc[r][s2];
            float xv = sdx[t * SPD + 2 * c4 + 1];
            float zv = sdx[t * SPD + 8 + c4];
            float y = (acc + dvc[c4] * xv) * siluf(zv);
            ygp[(size_t)(tc + t) * DI_ + dbase + c4] = f2b(y);
        }
    }
}

// ---------------- fused router + assign (sums 6 gl partials, fixed order) ----------------
__global__ __launch_bounds__(1024) void router_assign_k(const float* __restrict__ glp,
                                                        const float* __restrict__ rb2l,
                                                        float* __restrict__ tw,
                                                        int* __restrict__ glist,
                                                        int* __restrict__ tpos,
                                                        int* __restrict__ cnt,
                                                        float* __restrict__ statL)
{
    __shared__ float s_p[E_], s_c[E_];
    __shared__ int scnt[E_];
    int tid = threadIdx.x;
    if (tid < E_) { s_p[tid] = 0.f; s_c[tid] = 0.f; scnt[tid] = 0; }
    __syncthreads();
    float lp[E_] = {0.f, 0.f, 0.f, 0.f, 0.f, 0.f};
    float lc[E_] = {0.f, 0.f, 0.f, 0.f, 0.f, 0.f};
    for (int t = tid; t < BT_; t += 1024) {
        float g[E_];
        for (int e = 0; e < E_; e++) {
            float a = rb2l[e];
#pragma unroll
            for (int j = 0; j < 6; j++) a += glp[(size_t)j * (BT_ * E_) + t * E_ + e];
            g[e] = a;
        }
        int i0 = 0; float v0 = g[0];
        for (int e = 1; e < E_; e++) if (g[e] > v0) { v0 = g[e]; i0 = e; }
        int i1 = -1; float v1 = -1e30f;
        for (int e = 0; e < E_; e++) if (e != i0 && g[e] > v1) { v1 = g[e]; i1 = e; }
        if (i1 < 0) i1 = (i0 == 0) ? 1 : 0;
        float e1 = __expf(v1 - v0);
        float inv = 1.f / (1.f + e1);
        tw[t * 2] = inv; tw[t * 2 + 1] = e1 * inv;
        int pos0 = atomicAdd(&scnt[i0], 1);
        glist[i0 * BT_ + pos0] = t;
        tpos[2 * t] = i0 * BT_ + pos0;
        int pos1 = atomicAdd(&scnt[i1], 1);
        glist[i1 * BT_ + pos1] = t;
        tpos[2 * t + 1] = i1 * BT_ + pos1;
        float pb[E_], se = 0.f;
        for (int e = 0; e < E_; e++) { pb[e] = __expf(g[e] - v0); se += pb[e]; }
        float rse = 1.f / se;
#pragma unroll
        for (int e = 0; e < E_; e++) {
            lp[e] += pb[e] * rse;
            lc[e] += (i0 == e) ? 1.f : 0.f;
        }
    }
#pragma unroll
    for (int e = 0; e < E_; e++) {
        float v = lp[e], u = lc[e];
#pragma unroll
        for (int o = 32; o > 0; o >>= 1) { v += __shfl_xor(v, o); u += __shfl_xor(u, o); }
        if ((tid & 63) == 0) { atomicAdd(&s_p[e], v); atomicAdd(&s_c[e], u); }
    }
    __syncthreads();
    if (tid < E_) {
        cnt[tid] = scnt[tid];
        statL[tid] = s_p[tid];
        statL[8 + tid] = s_c[tid];
    }
}

__global__ void write_aux_k(const float* __restrict__ stats, float* __restrict__ out)
{
    if (threadIdx.x == 0 && blockIdx.x == 0) {
        float aux = 0.f;
        for (int l = 0; l < L_; l++) {
            float s = 0.f;
            for (int e = 0; e < E_; e++) s += stats[l * 16 + e] * stats[l * 16 + 8 + e];
            aux += 0.01f * (float)E_ * s / ((float)BT_ * (float)BT_);
        }
        out[BT_ * D_] = aux;
    }
}

// ---------------- launch ----------------
extern "C" void kernel_launch(void* const* d_in, const int* in_sizes, int n_in,
                              void* d_out, int out_size, void* d_ws, size_t ws_size,
                              hipStream_t stream)
{
    const float* x       = (const float*)d_in[0];
    const float* regime  = (const float*)d_in[1];
    const float* film_w1 = (const float*)d_in[2];
    const float* film_b1 = (const float*)d_in[3];
    const float* film_w2 = (const float*)d_in[4];
    const float* film_b2 = (const float*)d_in[5];
    const float* ssm_ng  = (const float*)d_in[6];
    const float* ssm_nb  = (const float*)d_in[7];
    const float* in_w    = (const float*)d_in[8];
    const float* xp_w    = (const float*)d_in[9];
    const float* dt_w    = (const float*)d_in[10];
    const float* dt_b    = (const float*)d_in[11];
    const float* alr     = (const float*)d_in[12];
    const float* aimp    = (const float*)d_in[13];
    const float* ssm_d   = (const float*)d_in[14];
    const float* out_w   = (const float*)d_in[15];
    const float* moe_ng  = (const float*)d_in[16];
    const float* moe_nb  = (const float*)d_in[17];
    const float* r_w1    = (const float*)d_in[18];
    const float* r_b1    = (const float*)d_in[19];
    const float* r_w2    = (const float*)d_in[20];
    const float* r_b2    = (const float*)d_in[21];
    const float* e_w1    = (const float*)d_in[22];
    const float* e_b1    = (const float*)d_in[23];
    const float* e_w2    = (const float*)d_in[24];
    const float* e_b2    = (const float*)d_in[25];
    const float* fin_g   = (const float*)d_in[26];
    const float* fin_b   = (const float*)d_in[27];

    float* ws = (float*)d_ws;
    size_t o = 0;
    float*  h      = ws + o; o += 786432;
    float*  stats  = ws + o; o += 64;
    ushort* xnH    = (ushort*)(ws + o); o += 393216;
    ushort* xnL    = (ushort*)(ws + o); o += 393216;
    float*  glp    = ws + o; o += 73728;    // [6][2048][6] gl partials
    float*  tw     = ws + o; o += 4096;
    int*    glist  = (int*)(ws + o); o += 12288;
    int*    tpos   = (int*)(ws + o); o += 4096;
    int*    cnt    = (int*)(ws + o); o += 16;
    ushort* in_wb  = (ushort*)(ws + o); o += 589824;
    ushort* xp_wb  = (ushort*)(ws + o); o += 67584;
    ushort* dt_wb  = (ushort*)(ws + o); o += 18432;   // written by conv_k, unused (dt fused)
    ushort* out_wb = (ushort*)(ws + o); o += 294912;
    ushort* e1b    = (ushort*)(ws + o); o += 1179648;
    ushort* e2b    = (ushort*)(ws + o); o += 1179648;
    ushort* r1h    = (ushort*)(ws + o); o += 147456;
    ushort* r1l    = (ushort*)(ws + o); o += 147456;
    // phase-aliased pool (SSM scratch / MoE scratch)
    float*  xz    = ws + o;                            // [2048][1536] f32 = 3145728 f
    ushort* xzb   = (ushort*)(ws + o + 3145728);       // [2048][768] bf16 = 786432 f
    ushort* xdblb = (ushort*)(ws + o + 3932160);       // [2048][32] bf16 = 32768 f
    float*  bcint = ws + o + 3964928;                  // [2048][64] f32 = 131072 f
    ushort* ygb   = (ushort*)(ws + o + 4096000);       // [2048][768] bf16 -> 4882432
    ushort* eohb  = (ushort*)(ws + o + 786432);        // [6][2048][512] bf16 (MoE phase)
    ushort* eodb  = (ushort*)(ws + o + 3932160);       // [6][2048][384] bf16 -> 5111808
    float*  gb    = ws + o;                            // film temp (pool, pre-loop)

    conv_k<<<2048, 256, 0, stream>>>(in_w, xp_w, dt_w, out_w, e_w1, e_w2, r_w1,
                                     in_wb, xp_wb, dt_wb, out_wb, e1b, e2b, r1h, r1l);
    film_k<<<B_, 2 * D_, 0, stream>>>(regime, film_w1, film_b1, film_w2, film_b2, gb, stats);
    film_apply_k<<<(B_ * T_ * D_ + 255) / 256, 256, 0, stream>>>(x, gb, h);

    for (int l = 0; l < L_; l++) {
        // ---- SSM block ----
        if (l == 0)
            ln_k<1><<<BT_, 256, 0, stream>>>(h, ssm_ng, ssm_nb, nullptr, xnH, nullptr);
        gemm_b<2, false, false, false><<<dim3(24, 32), 256, 0, stream>>>(
            xnH, D_, 0, in_wb + (size_t)l * 589824, 2 * DI_, 0,
            xz, 2 * DI_, 0, xzb, DI_, 0, DI_,
            nullptr, 0, nullptr, nullptr, 2 * DI_, D_, 0, 0);
        gemm_b<3, true, false, false><<<dim3(2, 32), 256, 0, stream>>>(
            xzb, DI_, 0, xp_wb + (size_t)l * 67584, XPN_, 0,
            bcint, 64, 0, xdblb, 32, 0, 32,
            nullptr, 0, nullptr, nullptr, XPN_, DI_, 0, 0);
        scan_k<<<B_ * 192, 128, 0, stream>>>(
            xz, xdblb, bcint,
            dt_w + (size_t)l * DTR_ * DI_, dt_b + l * DI_,
            alr + (size_t)l * DI_ * S_, aimp + (size_t)l * DI_ * S_,
            ssm_d + l * DI_, ygb);
        gemm_b<0, false, false, false><<<dim3(6, 32), 256, 0, stream>>>(
            ygb, DI_, 0, out_wb + (size_t)l * 294912, D_, 0,
            h, D_, 0, nullptr, 0, 0, 0,
            nullptr, 0, nullptr, nullptr, D_, DI_, 0, 1);

        // ---- MoE block ----
        ln_k<2><<<BT_, 256, 0, stream>>>(h, moe_ng + l * D_, moe_nb + l * D_, nullptr, xnH, xnL);
        gemm3_k<<<dim3(6, 32), 256, 0, stream>>>(
            xnH, xnL, D_, r1h + (size_t)l * 147456, r1l + (size_t)l * 147456, D_,
            r_b1 + l * D_,
            regime, r_w1 + (size_t)l * ((D_ + R_) * D_) + (size_t)D_ * D_,
            r_w2 + (size_t)l * D_ * E_,
            glp, D_);
        router_assign_k<<<1, 1024, 0, stream>>>(glp, r_b2 + l * E_, tw, glist, tpos, cnt, stats + l * 16);
        gemm_b<1, false, false, true><<<dim3(8, 32, 6), 256, 0, stream>>>(
            xnH, D_, 0, e1b + (size_t)l * 1179648, H_, (long)D_ * H_,
            nullptr, 0, 0, eohb, H_, (long)BT_ * H_, H_,
            e_b1 + (size_t)l * E_ * H_, H_, glist, cnt, H_, D_, 1, 0);
        gemm_b<1, false, false, false><<<dim3(6, 32, 6), 256, 0, stream>>>(
            eohb, H_, (long)BT_ * H_, e2b + (size_t)l * 1179648, D_, (long)H_ * D_,
            nullptr, 0, 0, eodb, D_, (long)BT_ * D_, D_,
            e_b2 + (size_t)l * E_ * D_, D_, nullptr, cnt, D_, H_, 0, 0);
        if (l < L_ - 1)
            selln_k<1><<<BT_, 256, 0, stream>>>(h, eodb, tw, tpos,
                ssm_ng + (l + 1) * D_, ssm_nb + (l + 1) * D_, nullptr, xnH, nullptr);
        else
            selln_k<0><<<BT_, 256, 0, stream>>>(h, eodb, tw, tpos,
                fin_g, fin_b, (float*)d_out, nullptr, nullptr);
    }

    write_aux_k<<<1, 64, 0, stream>>>(stats, (float*)d_out);
}

// Round 15
// 472.501 us; speedup vs baseline: 1.2964x; 1.0120x over previous
//
#include <hip/hip_runtime.h>
#include <hip/hip_bf16.h>
#include <math.h>

#define B_   4
#define T_   512
#define D_   384
#define S_   32
#define E_   6
#define H_   512
#define R_   5
#define L_   2
#define DI_  768
#define DTR_ 24
#define BT_  2048
#define XPN_ 88   // DTR + 2*S
#define SCH  64   // scan time-chunk
#define PIT  40   // GEMM LDS row pitch in ushorts (80 B)
#define SPD  12   // scan sdx pitch: [t][{dt,x}x4ch | z x4ch]
#define SPB  66   // scan sbc pitch: [t][{B,C}x32s]

typedef short s8v __attribute__((ext_vector_type(8)));
typedef float f32x4 __attribute__((ext_vector_type(4)));
typedef ushort u16x8 __attribute__((ext_vector_type(8)));

__device__ __forceinline__ float siluf(float x) { return x / (1.f + __expf(-x)); }
__device__ __forceinline__ ushort f2b(float f) {
    unsigned u = __float_as_uint(f);
    return (ushort)((u + 0x7FFFu + ((u >> 16) & 1u)) >> 16);
}
__device__ __forceinline__ float b2f(ushort h) { return __uint_as_float(((unsigned)h) << 16); }

// ---------------- weight pre-conversion (dt_w no longer converted: dt fused in scan) ----------------
#define CN0 1179648L  // in_w
#define CN1 135168L   // xp_w
#define CN3 589824L   // out_w
#define CN4 2359296L  // e_w1
#define CN5 2359296L  // e_w2
#define CN6 294912L   // r_w1[:384,:] hi/lo (2 layers)
__global__ void conv_k(const float* __restrict__ in_w, const float* __restrict__ xp_w,
                       const float* __restrict__ out_w,
                       const float* __restrict__ e_w1, const float* __restrict__ e_w2,
                       const float* __restrict__ r_w1,
                       ushort* __restrict__ in_wb, ushort* __restrict__ xp_wb,
                       ushort* __restrict__ out_wb,
                       ushort* __restrict__ e1b, ushort* __restrict__ e2b,
                       ushort* __restrict__ r1h, ushort* __restrict__ r1l)
{
    const long total = CN0 + CN1 + CN3 + CN4 + CN5 + CN6;
    long stride = (long)gridDim.x * 256;
    for (long i = (long)blockIdx.x * 256 + threadIdx.x; i < total; i += stride) {
        long j = i;
        if (j < CN0) { in_wb[j] = f2b(in_w[j]); continue; }
        j -= CN0;
        if (j < CN1) { xp_wb[j] = f2b(xp_w[j]); continue; }
        j -= CN1;
        if (j < CN3) { out_wb[j] = f2b(out_w[j]); continue; }
        j -= CN3;
        if (j < CN4) { e1b[j] = f2b(e_w1[j]); continue; }
        j -= CN4;
        if (j < CN5) { e2b[j] = f2b(e_w2[j]); continue; }
        j -= CN5;
        {
            long l = j / 147456, rem = j - l * 147456;
            float v = r_w1[l * (long)((D_ + R_) * D_) + rem];
            ushort hv = f2b(v);
            r1h[j] = hv;
            r1l[j] = f2b(v - b2f(hv));
        }
    }
}

// ---------------- FiLM ----------------
__global__ void film_k(const float* __restrict__ regime, const float* __restrict__ w1,
                       const float* __restrict__ b1, const float* __restrict__ w2,
                       const float* __restrict__ b2, float* __restrict__ gb,
                       float* __restrict__ stats)
{
    int b = blockIdx.x;
    int tid = threadIdx.x;
    if (b == 0 && tid < 40) stats[tid] = 0.f;
    __shared__ float t1[D_];
    if (tid < D_) {
        float a = b1[tid];
        for (int r = 0; r < R_; r++) a += regime[b * R_ + r] * w1[r * D_ + tid];
        t1[tid] = siluf(a);
    }
    __syncthreads();
    float a = b2[tid];
    for (int d = 0; d < D_; d++) a += t1[d] * w2[d * (2 * D_) + tid];
    gb[b * (2 * D_) + tid] = a;
}

// ---------------- fused film_apply + first LayerNorm (bf16 out) ----------------
__global__ __launch_bounds__(256) void film_ln_k(const float* __restrict__ x,
                                                 const float* __restrict__ gb,
                                                 float* __restrict__ h,
                                                 const float* __restrict__ g, const float* __restrict__ b,
                                                 ushort* __restrict__ outH)
{
    int row = blockIdx.x;
    int tid = threadIdx.x;
    int bb = row / T_;
    const float* xp = x + (size_t)row * D_;
    const float* gbp = gb + bb * (2 * D_);
    float v0 = xp[tid] * (1.f + gbp[tid]) + gbp[D_ + tid];
    float v1 = 0.f;
    if (tid < D_ - 256) v1 = xp[256 + tid] * (1.f + gbp[256 + tid]) + gbp[D_ + 256 + tid];
    float* hp = h + (size_t)row * D_;
    hp[tid] = v0;
    if (tid < D_ - 256) hp[256 + tid] = v1;
    float s = v0 + v1, ss = v0 * v0 + v1 * v1;
#pragma unroll
    for (int o = 32; o > 0; o >>= 1) { s += __shfl_xor(s, o); ss += __shfl_xor(ss, o); }
    __shared__ float sb[8];
    int w = tid >> 6;
    if ((tid & 63) == 0) { sb[w] = s; sb[4 + w] = ss; }
    __syncthreads();
    s = sb[0] + sb[1] + sb[2] + sb[3];
    ss = sb[4] + sb[5] + sb[6] + sb[7];
    float mean = s * (1.f / D_);
    float var = ss * (1.f / D_) - mean * mean;
    float rstd = rsqrtf(var + 1e-5f);
    outH[(size_t)row * D_ + tid] = f2b((v0 - mean) * rstd * g[tid] + b[tid]);
    if (tid < D_ - 256)
        outH[(size_t)row * D_ + 256 + tid] = f2b((v1 - mean) * rstd * g[256 + tid] + b[256 + tid]);
}

// ---------------- LayerNorm: MODE 0 = f32 out, 1 = bf16 out, 2 = bf16 hi+lo ----------------
template<int MODE>
__global__ __launch_bounds__(256) void ln_k(const float* __restrict__ in,
                                            const float* __restrict__ g, const float* __restrict__ b,
                                            float* __restrict__ outF,
                                            ushort* __restrict__ outH, ushort* __restrict__ outL)
{
    int row = blockIdx.x;
    int tid = threadIdx.x;
    const float* x = in + (size_t)row * D_;
    float v0 = x[tid];
    float v1 = (tid < D_ - 256) ? x[256 + tid] : 0.f;
    float s = v0 + v1, ss = v0 * v0 + v1 * v1;
#pragma unroll
    for (int o = 32; o > 0; o >>= 1) { s += __shfl_xor(s, o); ss += __shfl_xor(ss, o); }
    __shared__ float sb[8];
    int w = tid >> 6;
    if ((tid & 63) == 0) { sb[w] = s; sb[4 + w] = ss; }
    __syncthreads();
    s = sb[0] + sb[1] + sb[2] + sb[3];
    ss = sb[4] + sb[5] + sb[6] + sb[7];
    float mean = s * (1.f / D_);
    float var = ss * (1.f / D_) - mean * mean;
    float rstd = rsqrtf(var + 1e-5f);
#pragma unroll
    for (int p = 0; p < 2; p++) {
        int c = tid + p * 256;
        if (c >= D_) break;
        float v = (p ? v1 : v0);
        float o = (v - mean) * rstd * g[c] + b[c];
        size_t idx = (size_t)row * D_ + c;
        if (MODE == 0) outF[idx] = o;
        else {
            ushort hv = f2b(o);
            outH[idx] = hv;
            if (MODE == 2) outL[idx] = f2b(o - b2f(hv));
        }
    }
}

// ---------------- fused sel + LayerNorm (+aux on MODE 0) ----------------
template<int MODE>
__global__ __launch_bounds__(256) void selln_k(float* __restrict__ h,
                                               const ushort* __restrict__ eodb,
                                               const float* __restrict__ tw,
                                               const int* __restrict__ tpos,
                                               const float* __restrict__ g, const float* __restrict__ b,
                                               float* __restrict__ outF,
                                               ushort* __restrict__ outH, ushort* __restrict__ outL,
                                               const float* __restrict__ stats)
{
    int row = blockIdx.x;
    int tid = threadIdx.x;
    if (MODE == 0 && row == 0 && tid == 0) {
        float aux = 0.f;
        for (int l = 0; l < L_; l++) {
            float s2 = 0.f;
            for (int e = 0; e < E_; e++) s2 += stats[l * 16 + e] * stats[l * 16 + 8 + e];
            aux += 0.01f * (float)E_ * s2 / ((float)BT_ * (float)BT_);
        }
        outF[BT_ * D_] = aux;
    }
    float* hp = h + (size_t)row * D_;
    int p0 = tpos[row * 2], p1 = tpos[row * 2 + 1];
    float w0 = tw[row * 2], w1 = tw[row * 2 + 1];
    const ushort* e0 = eodb + (size_t)p0 * D_;
    const ushort* e1 = eodb + (size_t)p1 * D_;
    float v0 = hp[tid] + w0 * b2f(e0[tid]) + w1 * b2f(e1[tid]);
    float v1 = 0.f;
    if (tid < D_ - 256) v1 = hp[256 + tid] + w0 * b2f(e0[256 + tid]) + w1 * b2f(e1[256 + tid]);
    hp[tid] = v0;
    if (tid < D_ - 256) hp[256 + tid] = v1;
    float s = v0 + v1, ss = v0 * v0 + v1 * v1;
#pragma unroll
    for (int o = 32; o > 0; o >>= 1) { s += __shfl_xor(s, o); ss += __shfl_xor(ss, o); }
    __shared__ float sb[8];
    int w = tid >> 6;
    if ((tid & 63) == 0) { sb[w] = s; sb[4 + w] = ss; }
    __syncthreads();
    s = sb[0] + sb[1] + sb[2] + sb[3];
    ss = sb[4] + sb[5] + sb[6] + sb[7];
    float mean = s * (1.f / D_);
    float var = ss * (1.f / D_) - mean * mean;
    float rstd = rsqrtf(var + 1e-5f);
#pragma unroll
    for (int p = 0; p < 2; p++) {
        int c = tid + p * 256;
        if (c >= D_) break;
        float v = (p ? v1 : v0);
        float o = (v - mean) * rstd * g[c] + b[c];
        size_t idx = (size_t)row * D_ + c;
        if (MODE == 0) outF[idx] = o;
        else {
            ushort hv = f2b(o);
            outH[idx] = hv;
            if (MODE == 2) outL[idx] = f2b(o - b2f(hv));
        }
    }
}

// ---------------- bf16 MFMA GEMM, 64x64 tile, double-buffered LDS ----------------
// OM: 0 = f32 out, 1 = bf16 out, 2 = both, 3 = xp-special (bf16 col<nb16 + bcint scatter col>=24)
template<int OM, bool NG, bool KG, bool GATHER>
__global__ __launch_bounds__(256) void gemm_b(
    const ushort* __restrict__ A, int lda, long aOff,
    const ushort* __restrict__ W, int ldw, long wOff,
    float* __restrict__ C, int ldc, long cOff,
    ushort* __restrict__ Cb, int ldcb, long cbOff, int nb16,
    const float* __restrict__ bias, long bOff,
    const int* __restrict__ glist, const int* __restrict__ gcnt,
    int N, int K, int act, int acc)
{
    __shared__ __align__(16) ushort As[2][64 * PIT];
    __shared__ __align__(16) ushort Bs[2][64 * PIT];
    const int z = blockIdx.z;
    const int bm = blockIdx.y * 64, bn = blockIdx.x * 64;
    int cnt = 0;
    if (gcnt) { cnt = gcnt[z]; if (bm >= cnt) return; }
    const int tid = threadIdx.x, w = tid >> 6, lane = tid & 63;
    const int wm = (w >> 1) * 32, wn = (w & 1) * 32;
    const int l16 = lane & 15, lk = lane >> 4;
    const int r0 = tid >> 2, c0 = (tid & 3) * 8;
    const ushort* Ab;
    if (GATHER) {
        int gr = bm + r0;
        int t_idx = (gr < cnt) ? glist[(size_t)z * BT_ + gr] : 0;
        Ab = A + (size_t)t_idx * lda;
    } else {
        Ab = A + (size_t)z * aOff + (size_t)(bm + r0) * lda;
    }
    const ushort* Wb = W + (size_t)z * wOff;

    f32x4 accv[2][2];
#pragma unroll
    for (int i = 0; i < 2; i++)
#pragma unroll
        for (int j = 0; j < 2; j++) accv[i][j] = (f32x4)0.f;

    u16x8 arg;
    ushort wrg[8];
    auto LOADA = [&](int k0) {
        arg = *reinterpret_cast<const u16x8*>(Ab + k0 + c0);
    };
    auto LOADW = [&](int k0) {
#pragma unroll
        for (int i = 0; i < 8; i++) {
            int kk = k0 + w * 8 + i;
            bool ok = (!KG || kk < K) && (!NG || (bn + lane) < N);
            wrg[i] = ok ? Wb[(size_t)kk * ldw + bn + lane] : (ushort)0;
        }
    };
    auto STORE = [&](int buf) {
        *reinterpret_cast<u16x8*>(&As[buf][r0 * PIT + c0]) = arg;
        *reinterpret_cast<ushort4*>(&Bs[buf][lane * PIT + w * 8]) =
            make_ushort4(wrg[0], wrg[1], wrg[2], wrg[3]);
        *reinterpret_cast<ushort4*>(&Bs[buf][lane * PIT + w * 8 + 4]) =
            make_ushort4(wrg[4], wrg[5], wrg[6], wrg[7]);
    };

    LOADA(0); LOADW(0); STORE(0);
    __syncthreads();
    const int NIT = (K + 31) / 32;
    for (int it = 0; it < NIT; it++) {
        int cur = it & 1;
        bool more = (it + 1 < NIT);
        if (more) { LOADA((it + 1) * 32); LOADW((it + 1) * 32); }
        s8v af[2], bfr[2];
#pragma unroll
        for (int mf = 0; mf < 2; mf++)
            af[mf] = *reinterpret_cast<const s8v*>(&As[cur][(wm + mf * 16 + l16) * PIT + lk * 8]);
#pragma unroll
        for (int nf = 0; nf < 2; nf++)
            bfr[nf] = *reinterpret_cast<const s8v*>(&Bs[cur][(wn + nf * 16 + l16) * PIT + lk * 8]);
#pragma unroll
        for (int mf = 0; mf < 2; mf++)
#pragma unroll
            for (int nf = 0; nf < 2; nf++)
                accv[mf][nf] = __builtin_amdgcn_mfma_f32_16x16x32_bf16(af[mf], bfr[nf], accv[mf][nf], 0, 0, 0);
        if (more) { STORE(cur ^ 1); __syncthreads(); }
    }

    const float* biasb = bias ? bias + (size_t)z * bOff : nullptr;
#pragma unroll
    for (int mf = 0; mf < 2; mf++) {
#pragma unroll
        for (int nf = 0; nf < 2; nf++) {
            int col = bn + wn + nf * 16 + l16;
            if (NG && col >= N) continue;
#pragma unroll
            for (int r = 0; r < 4; r++) {
                int rr = bm + wm + mf * 16 + lk * 4 + r;
                if (gcnt && rr >= cnt) continue;
                float v = accv[mf][nf][r];
                if (biasb) v += biasb[col];
                if (act == 1) v = siluf(v);
                else if (act == 2) v = (v > 0.f) ? v + log1pf(__expf(-v)) : log1pf(__expf(v));
                if (OM == 0 || OM == 2) {
                    float* Cz = C + (size_t)z * cOff;
                    size_t ci = (size_t)rr * ldc + col;
                    Cz[ci] = acc ? (Cz[ci] + v) : v;
                }
                if (OM == 1 || OM == 2) {
                    if (col < nb16)
                        (Cb + (size_t)z * cbOff)[(size_t)rr * ldcb + col] = f2b(v);
                }
                if (OM == 3) {
                    if (col < nb16)
                        Cb[(size_t)rr * ldcb + col] = f2b(v);
                    if (col >= 24) {        // bcint scatter: {B[s],C[s]} interleaved
                        int q = col - 24;
                        C[(size_t)rr * 64 + ((q < 32) ? (2 * q) : (2 * (q - 32) + 1))] = v;
                    }
                }
            }
        }
    }
}

// ---------------- bf16x3 router GEMM + fused gate-logit partials ----------------
__global__ __launch_bounds__(256) void gemm3_k(
    const ushort* __restrict__ Ah, const ushort* __restrict__ Al, int lda,
    const ushort* __restrict__ Wh, const ushort* __restrict__ Wl, int ldw,
    const float* __restrict__ bias,
    const float* __restrict__ regime, const float* __restrict__ rw1t,
    const float* __restrict__ rw2l,
    float* __restrict__ glp,
    int K)
{
    __shared__ __align__(16) ushort sAh[64 * PIT], sAl[64 * PIT];
    __shared__ __align__(16) ushort sWh[64 * PIT], sWl[64 * PIT];
    __shared__ __align__(16) float sV[64 * 66];
    const int bm = blockIdx.y * 64, bn = blockIdx.x * 64;
    const int tid = threadIdx.x, w = tid >> 6, lane = tid & 63;
    const int wm = (w >> 1) * 32, wn = (w & 1) * 32;
    const int l16 = lane & 15, lk = lane >> 4;
    const int r0 = tid >> 2, c0 = (tid & 3) * 8;
    f32x4 accv[2][2];
#pragma unroll
    for (int i = 0; i < 2; i++)
#pragma unroll
        for (int j = 0; j < 2; j++) accv[i][j] = (f32x4)0.f;

    for (int k0 = 0; k0 < K; k0 += 32) {
        *reinterpret_cast<u16x8*>(&sAh[r0 * PIT + c0]) =
            *reinterpret_cast<const u16x8*>(Ah + (size_t)(bm + r0) * lda + k0 + c0);
        *reinterpret_cast<u16x8*>(&sAl[r0 * PIT + c0]) =
            *reinterpret_cast<const u16x8*>(Al + (size_t)(bm + r0) * lda + k0 + c0);
        {
            ushort th[8], tl[8];
#pragma unroll
            for (int i = 0; i < 8; i++) {
                int kk = k0 + w * 8 + i;
                th[i] = Wh[(size_t)kk * ldw + bn + lane];
                tl[i] = Wl[(size_t)kk * ldw + bn + lane];
            }
            *reinterpret_cast<ushort4*>(&sWh[lane * PIT + w * 8])     = make_ushort4(th[0], th[1], th[2], th[3]);
            *reinterpret_cast<ushort4*>(&sWh[lane * PIT + w * 8 + 4]) = make_ushort4(th[4], th[5], th[6], th[7]);
            *reinterpret_cast<ushort4*>(&sWl[lane * PIT + w * 8])     = make_ushort4(tl[0], tl[1], tl[2], tl[3]);
            *reinterpret_cast<ushort4*>(&sWl[lane * PIT + w * 8 + 4]) = make_ushort4(tl[4], tl[5], tl[6], tl[7]);
        }
        __syncthreads();
        s8v ah[2], al[2], bh[2], bl[2];
#pragma unroll
        for (int mf = 0; mf < 2; mf++) {
            ah[mf] = *reinterpret_cast<const s8v*>(&sAh[(wm + mf * 16 + l16) * PIT + lk * 8]);
            al[mf] = *reinterpret_cast<const s8v*>(&sAl[(wm + mf * 16 + l16) * PIT + lk * 8]);
        }
#pragma unroll
        for (int nf = 0; nf < 2; nf++) {
            bh[nf] = *reinterpret_cast<const s8v*>(&sWh[(wn + nf * 16 + l16) * PIT + lk * 8]);
            bl[nf] = *reinterpret_cast<const s8v*>(&sWl[(wn + nf * 16 + l16) * PIT + lk * 8]);
        }
#pragma unroll
        for (int mf = 0; mf < 2; mf++)
#pragma unroll
            for (int nf = 0; nf < 2; nf++) {
                accv[mf][nf] = __builtin_amdgcn_mfma_f32_16x16x32_bf16(ah[mf], bh[nf], accv[mf][nf], 0, 0, 0);
                accv[mf][nf] = __builtin_amdgcn_mfma_f32_16x16x32_bf16(ah[mf], bl[nf], accv[mf][nf], 0, 0, 0);
                accv[mf][nf] = __builtin_amdgcn_mfma_f32_16x16x32_bf16(al[mf], bh[nf], accv[mf][nf], 0, 0, 0);
            }
        __syncthreads();
    }
    const float* rg = regime + (bm / T_) * R_;
#pragma unroll
    for (int nf = 0; nf < 2; nf++) {
        int col = bn + wn + nf * 16 + l16;
        float rb = bias[col];
#pragma unroll
        for (int r = 0; r < R_; r++) rb += rg[r] * rw1t[r * D_ + col];
#pragma unroll
        for (int mf = 0; mf < 2; mf++)
#pragma unroll
            for (int r = 0; r < 4; r++) {
                int rr = wm + mf * 16 + lk * 4 + r;
                sV[rr * 66 + (col - bn)] = siluf(accv[mf][nf][r] + rb);
            }
    }
    __syncthreads();
    for (int job = tid; job < 64 * E_; job += 256) {
        int row = job / E_, e = job - row * E_;
        float a = 0.f;
#pragma unroll 8
        for (int c = 0; c < 64; c++)
            a += sV[row * 66 + c] * rw2l[(size_t)(bn + c) * E_ + e];
        glp[(size_t)blockIdx.x * (BT_ * E_) + (size_t)(bm + row) * E_ + e] = a;
    }
}

// ---------------- SSM scan v8: fused dt, z in LDS, depth-4 operand ring ----------------
__global__ __launch_bounds__(128) void scan_k(
    const float* __restrict__ xz, const ushort* __restrict__ xdblb,
    const float* __restrict__ bcint,
    const float* __restrict__ dt_w, const float* __restrict__ dt_b,
    const float* __restrict__ alr, const float* __restrict__ aim,
    const float* __restrict__ dvecp, ushort* __restrict__ ygb)
{
    int p = blockIdx.x;
    int blk = (p & 7) * 96 + (p >> 3);       // 768 = 8*96, bijective XCD clustering
    int b = blk / 192;
    int dbase = (blk % 192) * 4;
    int tid = threadIdx.x;                   // 0..127
    int ch = tid >> 5;
    int s = tid & 31;
    int d = dbase + ch;
    __shared__ __align__(16) float sdx[64 * SPD];     // 3.0 KB: [t][dt,x x4 | z x4]
    __shared__ __align__(16) float sbc[64 * SPB];     // 16.5 KB
    __shared__ float sacc[SCH * 4][33];               // 33.8 KB  (total 53760 B, 3 blk/CU)
    int cch = tid & 3;
    float wdt[24];
#pragma unroll
    for (int k = 0; k < 24; k++) wdt[k] = dt_w[k * DI_ + dbase + cch];
    float dtbias = dt_b[dbase + cch];

    float negA = -__expf(alr[d * S_ + s]);
    float aimv = aim[d * S_ + s];
    float4 dv4 = *reinterpret_cast<const float4*>(dvecp + dbase);
    float dvc[4] = {dv4.x, dv4.y, dv4.z, dv4.w};
    float hre = 0.f, him = 0.f;
    const float* xzp = xz + (size_t)b * T_ * (2 * DI_);
    const ushort* xdp = xdblb + (size_t)b * T_ * 32;
    const float* bcp = bcint + (size_t)b * T_ * 64;
    ushort* ygp = ygb + (size_t)b * T_ * DI_;

    for (int c = 0; c < T_ / SCH; c++) {
        int tc = c * SCH;
        __syncthreads();
        if (tid < 64) {
            int t = tid;
            float4 x4 = *reinterpret_cast<const float4*>(xzp + (size_t)(tc + t) * (2 * DI_) + dbase);
            float4 z4 = *reinterpret_cast<const float4*>(xzp + (size_t)(tc + t) * (2 * DI_) + DI_ + dbase);
            sdx[t * SPD + 1] = x4.x;
            sdx[t * SPD + 3] = x4.y;
            sdx[t * SPD + 5] = x4.z;
            sdx[t * SPD + 7] = x4.w;
            sdx[t * SPD + 8]  = z4.x;
            sdx[t * SPD + 9]  = z4.y;
            sdx[t * SPD + 10] = z4.z;
            sdx[t * SPD + 11] = z4.w;
        }
        {
            int t0 = tid >> 2;
#pragma unroll
            for (int j = 0; j < 2; j++) {
                int t = t0 + j * 32;
                const ushort* xr = xdp + (size_t)(tc + t) * 32;
                u16x8 a0 = *reinterpret_cast<const u16x8*>(xr);
                u16x8 a1 = *reinterpret_cast<const u16x8*>(xr + 8);
                u16x8 a2 = *reinterpret_cast<const u16x8*>(xr + 16);
                float acc = dtbias;
#pragma unroll
                for (int k = 0; k < 8; k++) acc = fmaf(b2f((ushort)a0[k]), wdt[k], acc);
#pragma unroll
                for (int k = 0; k < 8; k++) acc = fmaf(b2f((ushort)a1[k]), wdt[8 + k], acc);
#pragma unroll
                for (int k = 0; k < 8; k++) acc = fmaf(b2f((ushort)a2[k]), wdt[16 + k], acc);
                float dtv = (acc > 0.f) ? acc + log1pf(__expf(-acc)) : log1pf(__expf(acc));
                sdx[t * SPD + 2 * cch] = dtv;
            }
        }
#pragma unroll
        for (int i = 0; i < 8; i++) {
            int idx = tid + i * 128;
            int tt = idx >> 4, q = idx & 15;
            *reinterpret_cast<float4*>(&sbc[tt * SPB + 4 * q]) =
                *reinterpret_cast<const float4*>(bcp + (size_t)(tc + tt) * 64 + 4 * q);
        }
        __syncthreads();

        // depth-4 operand ring: prefetch t+3 (covers ~full LDS latency)
        const float* dxr = &sdx[2 * ch];
        const float* bcr = &sbc[2 * s];
        float2 dxa = *reinterpret_cast<const float2*>(dxr);
        float2 bca = *reinterpret_cast<const float2*>(bcr);
        float2 dxb = *reinterpret_cast<const float2*>(dxr + SPD);
        float2 bcb = *reinterpret_cast<const float2*>(bcr + SPB);
        float2 dxc = *reinterpret_cast<const float2*>(dxr + 2 * SPD);
        float2 bcc = *reinterpret_cast<const float2*>(bcr + 2 * SPB);
#pragma unroll 4
        for (int t = 0; t < SCH; t++) {
            float2 dxn = make_float2(0.f, 0.f), bcn = dxn;
            if (t + 3 < SCH) {
                dxn = *reinterpret_cast<const float2*>(dxr + (t + 3) * SPD);
                bcn = *reinterpret_cast<const float2*>(bcr + (t + 3) * SPB);
            }
            float e = __expf(negA * dxa.x);
            float sn, cs;
            __sincosf(aimv * dxa.x, &sn, &cs);
            float dre = e * cs, dim = e * sn;
            float u = dxa.x * dxa.y * bca.x;
            float nre = fmaf(dre, hre, fmaf(-dim, him, u));
            him = fmaf(dre, him, dim * hre);
            hre = nre;
            sacc[t * 4 + ch][s] = hre * bca.y;
            dxa = dxb; bca = bcb;
            dxb = dxc; bcb = bcc;
            dxc = dxn; bcc = bcn;
        }
        __syncthreads();

#pragma unroll
        for (int p2 = 0; p2 < 2; p2++) {
            int r = tid + p2 * 128;
            int t = r >> 2, c4 = r & 3;
            float acc = 0.f;
#pragma unroll
            for (int s2 = 0; s2 < 32; s2++) acc += sacc[r][s2];
            float xv = sdx[t * SPD + 2 * c4 + 1];
            float zv = sdx[t * SPD + 8 + c4];
            float y = (acc + dvc[c4] * xv) * siluf(zv);
            ygp[(size_t)(tc + t) * DI_ + dbase + c4] = f2b(y);
        }
    }
}

// ---------------- fused router + assign (sums 6 gl partials, fixed order) ----------------
__global__ __launch_bounds__(1024) void router_assign_k(const float* __restrict__ glp,
                                                        const float* __restrict__ rb2l,
                                                        float* __restrict__ tw,
                                                        int* __restrict__ glist,
                                                        int* __restrict__ tpos,
                                                        int* __restrict__ cnt,
                                                        float* __restrict__ statL)
{
    __shared__ float s_p[E_], s_c[E_];
    __shared__ int scnt[E_];
    int tid = threadIdx.x;
    if (tid < E_) { s_p[tid] = 0.f; s_c[tid] = 0.f; scnt[tid] = 0; }
    __syncthreads();
    float lp[E_] = {0.f, 0.f, 0.f, 0.f, 0.f, 0.f};
    float lc[E_] = {0.f, 0.f, 0.f, 0.f, 0.f, 0.f};
    for (int t = tid; t < BT_; t += 1024) {
        float g[E_];
        for (int e = 0; e < E_; e++) {
            float a = rb2l[e];
#pragma unroll
            for (int j = 0; j < 6; j++) a += glp[(size_t)j * (BT_ * E_) + t * E_ + e];
            g[e] = a;
        }
        int i0 = 0; float v0 = g[0];
        for (int e = 1; e < E_; e++) if (g[e] > v0) { v0 = g[e]; i0 = e; }
        int i1 = -1; float v1 = -1e30f;
        for (int e = 0; e < E_; e++) if (e != i0 && g[e] > v1) { v1 = g[e]; i1 = e; }
        if (i1 < 0) i1 = (i0 == 0) ? 1 : 0;
        float e1 = __expf(v1 - v0);
        float inv = 1.f / (1.f + e1);
        tw[t * 2] = inv; tw[t * 2 + 1] = e1 * inv;
        int pos0 = atomicAdd(&scnt[i0], 1);
        glist[i0 * BT_ + pos0] = t;
        tpos[2 * t] = i0 * BT_ + pos0;
        int pos1 = atomicAdd(&scnt[i1], 1);
        glist[i1 * BT_ + pos1] = t;
        tpos[2 * t + 1] = i1 * BT_ + pos1;
        float pb[E_], se = 0.f;
        for (int e = 0; e < E_; e++) { pb[e] = __expf(g[e] - v0); se += pb[e]; }
        float rse = 1.f / se;
#pragma unroll
        for (int e = 0; e < E_; e++) {
            lp[e] += pb[e] * rse;
            lc[e] += (i0 == e) ? 1.f : 0.f;
        }
    }
#pragma unroll
    for (int e = 0; e < E_; e++) {
        float v = lp[e], u = lc[e];
#pragma unroll
        for (int o = 32; o > 0; o >>= 1) { v += __shfl_xor(v, o); u += __shfl_xor(u, o); }
        if ((tid & 63) == 0) { atomicAdd(&s_p[e], v); atomicAdd(&s_c[e], u); }
    }
    __syncthreads();
    if (tid < E_) {
        cnt[tid] = scnt[tid];
        statL[tid] = s_p[tid];
        statL[8 + tid] = s_c[tid];
    }
}

// ---------------- launch ----------------
extern "C" void kernel_launch(void* const* d_in, const int* in_sizes, int n_in,
                              void* d_out, int out_size, void* d_ws, size_t ws_size,
                              hipStream_t stream)
{
    const float* x       = (const float*)d_in[0];
    const float* regime  = (const float*)d_in[1];
    const float* film_w1 = (const float*)d_in[2];
    const float* film_b1 = (const float*)d_in[3];
    const float* film_w2 = (const float*)d_in[4];
    const float* film_b2 = (const float*)d_in[5];
    const float* ssm_ng  = (const float*)d_in[6];
    const float* ssm_nb  = (const float*)d_in[7];
    const float* in_w    = (const float*)d_in[8];
    const float* xp_w    = (const float*)d_in[9];
    const float* dt_w    = (const float*)d_in[10];
    const float* dt_b    = (const float*)d_in[11];
    const float* alr     = (const float*)d_in[12];
    const float* aimp    = (const float*)d_in[13];
    const float* ssm_d   = (const float*)d_in[14];
    const float* out_w   = (const float*)d_in[15];
    const float* moe_ng  = (const float*)d_in[16];
    const float* moe_nb  = (const float*)d_in[17];
    const float* r_w1    = (const float*)d_in[18];
    const float* r_b1    = (const float*)d_in[19];
    const float* r_w2    = (const float*)d_in[20];
    const float* r_b2    = (const float*)d_in[21];
    const float* e_w1    = (const float*)d_in[22];
    const float* e_b1    = (const float*)d_in[23];
    const float* e_w2    = (const float*)d_in[24];
    const float* e_b2    = (const float*)d_in[25];
    const float* fin_g   = (const float*)d_in[26];
    const float* fin_b   = (const float*)d_in[27];

    float* ws = (float*)d_ws;
    size_t o = 0;
    float*  h      = ws + o; o += 786432;
    float*  stats  = ws + o; o += 64;
    ushort* xnH    = (ushort*)(ws + o); o += 393216;
    ushort* xnL    = (ushort*)(ws + o); o += 393216;
    float*  glp    = ws + o; o += 73728;    // [6][2048][6] gl partials
    float*  tw     = ws + o; o += 4096;
    int*    glist  = (int*)(ws + o); o += 12288;
    int*    tpos   = (int*)(ws + o); o += 4096;
    int*    cnt    = (int*)(ws + o); o += 16;
    ushort* in_wb  = (ushort*)(ws + o); o += 589824;
    ushort* xp_wb  = (ushort*)(ws + o); o += 67584;
    ushort* out_wb = (ushort*)(ws + o); o += 294912;
    ushort* e1b    = (ushort*)(ws + o); o += 1179648;
    ushort* e2b    = (ushort*)(ws + o); o += 1179648;
    ushort* r1h    = (ushort*)(ws + o); o += 147456;
    ushort* r1l    = (ushort*)(ws + o); o += 147456;
    // phase-aliased pool (SSM scratch / MoE scratch)
    float*  xz    = ws + o;                            // [2048][1536] f32 = 3145728 f
    ushort* xzb   = (ushort*)(ws + o + 3145728);       // [2048][768] bf16 = 786432 f
    ushort* xdblb = (ushort*)(ws + o + 3932160);       // [2048][32] bf16 = 32768 f
    float*  bcint = ws + o + 3964928;                  // [2048][64] f32 = 131072 f
    ushort* ygb   = (ushort*)(ws + o + 4096000);       // [2048][768] bf16 -> 4882432
    ushort* eohb  = (ushort*)(ws + o + 786432);        // [6][2048][512] bf16 (MoE phase)
    ushort* eodb  = (ushort*)(ws + o + 3932160);       // [6][2048][384] bf16 -> 5111808
    float*  gb    = ws + o;                            // film temp (pool, pre-loop)

    conv_k<<<2048, 256, 0, stream>>>(in_w, xp_w, out_w, e_w1, e_w2, r_w1,
                                     in_wb, xp_wb, out_wb, e1b, e2b, r1h, r1l);
    film_k<<<B_, 2 * D_, 0, stream>>>(regime, film_w1, film_b1, film_w2, film_b2, gb, stats);
    film_ln_k<<<BT_, 256, 0, stream>>>(x, gb, h, ssm_ng, ssm_nb, xnH);

    for (int l = 0; l < L_; l++) {
        // ---- SSM block ----  (xnH ready: film_ln_k for l==0, selln_k<1> for l>0)
        gemm_b<2, false, false, false><<<dim3(24, 32), 256, 0, stream>>>(
            xnH, D_, 0, in_wb + (size_t)l * 589824, 2 * DI_, 0,
            xz, 2 * DI_, 0, xzb, DI_, 0, DI_,
            nullptr, 0, nullptr, nullptr, 2 * DI_, D_, 0, 0);
        gemm_b<3, true, false, false><<<dim3(2, 32), 256, 0, stream>>>(
            xzb, DI_, 0, xp_wb + (size_t)l * 67584, XPN_, 0,
            bcint, 64, 0, xdblb, 32, 0, 32,
            nullptr, 0, nullptr, nullptr, XPN_, DI_, 0, 0);
        scan_k<<<B_ * 192, 128, 0, stream>>>(
            xz, xdblb, bcint,
            dt_w + (size_t)l * DTR_ * DI_, dt_b + l * DI_,
            alr + (size_t)l * DI_ * S_, aimp + (size_t)l * DI_ * S_,
            ssm_d + l * DI_, ygb);
        gemm_b<0, false, false, false><<<dim3(6, 32), 256, 0, stream>>>(
            ygb, DI_, 0, out_wb + (size_t)l * 294912, D_, 0,
            h, D_, 0, nullptr, 0, 0, 0,
            nullptr, 0, nullptr, nullptr, D_, DI_, 0, 1);

        // ---- MoE block ----
        ln_k<2><<<BT_, 256, 0, stream>>>(h, moe_ng + l * D_, moe_nb + l * D_, nullptr, xnH, xnL);
        gemm3_k<<<dim3(6, 32), 256, 0, stream>>>(
            xnH, xnL, D_, r1h + (size_t)l * 147456, r1l + (size_t)l * 147456, D_,
            r_b1 + l * D_,
            regime, r_w1 + (size_t)l * ((D_ + R_) * D_) + (size_t)D_ * D_,
            r_w2 + (size_t)l * D_ * E_,
            glp, D_);
        router_assign_k<<<1, 1024, 0, stream>>>(glp, r_b2 + l * E_, tw, glist, tpos, cnt, stats + l * 16);
        gemm_b<1, false, false, true><<<dim3(8, 32, 6), 256, 0, stream>>>(
            xnH, D_, 0, e1b + (size_t)l * 1179648, H_, (long)D_ * H_,
            nullptr, 0, 0, eohb, H_, (long)BT_ * H_, H_,
            e_b1 + (size_t)l * E_ * H_, H_, glist, cnt, H_, D_, 1, 0);
        gemm_b<1, false, false, false><<<dim3(6, 32, 6), 256, 0, stream>>>(
            eohb, H_, (long)BT_ * H_, e2b + (size_t)l * 1179648, D_, (long)H_ * D_,
            nullptr, 0, 0, eodb, D_, (long)BT_ * D_, D_,
            e_b2 + (size_t)l * E_ * D_, D_, nullptr, cnt, D_, H_, 0, 0);
        if (l < L_ - 1)
            selln_k<1><<<BT_, 256, 0, stream>>>(h, eodb, tw, tpos,
                ssm_ng + (l + 1) * D_, ssm_nb + (l + 1) * D_, nullptr, xnH, nullptr, nullptr);
        else
            selln_k<0><<<BT_, 256, 0, stream>>>(h, eodb, tw, tpos,
                fin_g, fin_b, (float*)d_out, nullptr, nullptr, stats);
    }
}